// Round 3
// baseline (459.949 us; speedup 1.0000x reference)
//
#include <hip/hip_runtime.h>
#include <math.h>

constexpr int kB  = 16;
constexpr int kS  = 256;
constexpr int kD  = 1024;
constexpr int kH  = 16;
constexpr float kScale = 0.125f;  // 1/sqrt(64)

using bf16x8  = __attribute__((ext_vector_type(8))) short;
using floatx4 = __attribute__((ext_vector_type(4))) float;
typedef unsigned short u16;

__device__ __forceinline__ u16 f2bf(float x) {
  union { float f; unsigned u; } v; v.f = x;
  unsigned r = v.u + 0x7fffu + ((v.u >> 16) & 1u);
  return (u16)(r >> 16);
}
__device__ __forceinline__ float bf2f(u16 h) {
  union { unsigned u; float f; } v; v.u = ((unsigned)h) << 16;
  return v.f;
}

#define MFMA16(a, b, c) __builtin_amdgcn_mfma_f32_16x16x32_bf16((a), (b), (c), 0, 0, 0)
#define GLL16(gp, lp)                                                        \
  __builtin_amdgcn_global_load_lds(                                          \
      (const __attribute__((address_space(1))) unsigned int*)(gp),           \
      (__attribute__((address_space(3))) unsigned int*)(lp), 16, 0, 0)

// ---------------- sinusoid table rows: p in [0,256), pos = p-255, bf16 out --------
__global__ __launch_bounds__(256) void make_table_k(u16* __restrict__ T) {
  int idx = blockIdx.x * 256 + threadIdx.x;  // < 256*1024
  int p = idx >> 10;
  int i = idx & 1023;
  float ex = (float)(2 * (i / 2)) * (1.0f / 1024.0f);
  float scale = exp2f(ex * -13.287712379549449f);  // 10000^-ex
  float angle = (float)(p - 255) * scale;
  float v = (i & 1) ? cosf(angle) : sinf(angle);
  T[idx] = f2bf(v);
}

// ---------------- cast/pack (x4 vectorized) ----------------
__global__ __launch_bounds__(256) void pack_k(
    const float* __restrict__ x, const float* __restrict__ Wq,
    const float* __restrict__ Wk, const float* __restrict__ Wv,
    const float* __restrict__ Wr, const float* __restrict__ Wo,
    const float* __restrict__ bq, const float* __restrict__ bk,
    const float* __restrict__ bv, const float* __restrict__ br,
    u16* __restrict__ xb, u16* __restrict__ W4b, u16* __restrict__ Wob,
    float* __restrict__ b4) {
  size_t i = ((size_t)blockIdx.x * 256 + threadIdx.x) * 4;
  const size_t NX = (size_t)4194304, NW = (size_t)1048576;
  const float* src;
  u16* dst;
  size_t o;
  if (i < NX) {
    src = x; dst = xb; o = i;
  } else if (i < NX + 4 * NW) {
    size_t j = i - NX;
    int sel = (int)(j >> 20);
    o = j & (NW - 1);
    src = sel == 0 ? Wq : sel == 1 ? Wk : sel == 2 ? Wv : Wr;
    dst = W4b + (size_t)sel * NW;
  } else if (i < NX + 5 * NW) {
    o = i - NX - 4 * NW;
    src = Wo; dst = Wob;
  } else if (i < NX + 5 * NW + 4096) {
    size_t j = i - NX - 5 * NW;
    int sel = (int)(j >> 10);
    o = j & 1023;
    src = sel == 0 ? bq : sel == 1 ? bk : sel == 2 ? bv : br;
    *reinterpret_cast<float4*>(b4 + j) = *reinterpret_cast<const float4*>(src + o);
    return;
  } else {
    return;
  }
  float4 v = *reinterpret_cast<const float4*>(src + o);
  ushort4 r;
  r.x = f2bf(v.x); r.y = f2bf(v.y); r.z = f2bf(v.z); r.w = f2bf(v.w);
  *reinterpret_cast<ushort4*>(dst + o) = r;
}

// ---------------- bf16 MFMA GEMM: C = A @ W^T + bias ----------------
template <int OUT_BF16>
__global__ __launch_bounds__(256) void gemm_k(
    const u16* __restrict__ A, const u16* __restrict__ W,
    const float* __restrict__ bias, void* __restrict__ Cv,
    int M, int N, int K) {
  __shared__ u16 Alds[128 * 64];
  __shared__ u16 Blds[128 * 64];
  const int bm = blockIdx.y * 128, bn = blockIdx.x * 128;
  const int t = threadIdx.x, w = t >> 6, l = t & 63;
  const int l15 = l & 15, quad = l >> 4;
  const int wm = w >> 1, wn = w & 1;
  const int lrow8 = l >> 3;
  const int kslot = l & 7;

  floatx4 acc[4][4] = {};

  for (int k0 = 0; k0 < K; k0 += 64) {
#pragma unroll
    for (int sg = 0; sg < 4; ++sg) {
      int mrow = sg * 32 + w * 8 + lrow8;
      int gk = (kslot ^ (mrow & 7)) << 3;
      const u16* gpa = A + (size_t)(bm + mrow) * K + k0 + gk;
      const u16* gpb = W + (size_t)(bn + mrow) * K + k0 + gk;
      u16* lpa = Alds + (sg * 32 + w * 8) * 64;
      u16* lpb = Blds + (sg * 32 + w * 8) * 64;
      GLL16(gpa, lpa);
      GLL16(gpb, lpb);
    }
    __syncthreads();
#pragma unroll
    for (int c = 0; c < 2; ++c) {
      bf16x8 af[4], bf[4];
#pragma unroll
      for (int mi = 0; mi < 4; ++mi) {
        int am = wm * 64 + mi * 16 + l15;
        af[mi] = *(const bf16x8*)(Alds + am * 64 + (((c * 4 + quad) ^ (am & 7)) << 3));
      }
#pragma unroll
      for (int ni = 0; ni < 4; ++ni) {
        int an = wn * 64 + ni * 16 + l15;
        bf[ni] = *(const bf16x8*)(Blds + an * 64 + (((c * 4 + quad) ^ (an & 7)) << 3));
      }
#pragma unroll
      for (int mi = 0; mi < 4; ++mi)
#pragma unroll
        for (int ni = 0; ni < 4; ++ni)
          acc[mi][ni] = MFMA16(af[mi], bf[ni], acc[mi][ni]);
    }
    __syncthreads();
  }

#pragma unroll
  for (int ni = 0; ni < 4; ++ni) {
    int col = bn + wn * 64 + ni * 16 + l15;
    float bv = bias[col];
#pragma unroll
    for (int mi = 0; mi < 4; ++mi) {
      int mrow = bm + wm * 64 + mi * 16 + quad * 4;
#pragma unroll
      for (int r = 0; r < 4; ++r) {
        float v = acc[mi][ni][r] + bv;
        if (OUT_BF16)
          ((u16*)Cv)[(size_t)(mrow + r) * N + col] = f2bf(v);
        else
          ((float*)Cv)[(size_t)(mrow + r) * N + col] = v;
      }
    }
  }
}

// ---------------- V transpose: Vt[b][d][z] <- QKVR[(b*S+z)*4096 + 2048 + d] -------
__global__ __launch_bounds__(256) void transpose_v_k(const u16* __restrict__ Q4,
                                                     u16* __restrict__ Vt) {
  __shared__ u16 tile[32][36];
  int blk = blockIdx.x;
  int dt6 = blk & 31;
  int zt  = (blk >> 5) & 7;
  int b   = blk >> 8;
  int t = threadIdx.x;
  int r = t >> 3, cc = t & 7;
  const u16* gp = Q4 + (size_t)(b * 256 + zt * 32 + r) * 4096 + 2048 + dt6 * 32 + cc * 4;
  ushort4 vv = *(const ushort4*)gp;
  tile[r][cc * 4 + 0] = vv.x;
  tile[r][cc * 4 + 1] = vv.y;
  tile[r][cc * 4 + 2] = vv.z;
  tile[r][cc * 4 + 3] = vv.w;
  __syncthreads();
  ushort4 o;
  o.x = tile[cc * 4 + 0][r];
  o.y = tile[cc * 4 + 1][r];
  o.z = tile[cc * 4 + 2][r];
  o.w = tile[cc * 4 + 3][r];
  u16* op = Vt + (size_t)b * 262144 + (size_t)(dt6 * 32 + r) * 256 + zt * 32 + cc * 4;
  *(ushort4*)op = o;
}

// ---------------- small bias-dot terms ----------------
// ut[(b*H+h)*256 + z] = u_bias[h] . KR[b,z,h,:]
// dt[h*256 + p]       = v_bias[h] . RPR[p,h,:]
__global__ __launch_bounds__(256) void bias_terms_k(
    const u16* __restrict__ QKVR, const u16* __restrict__ RPR,
    const float* __restrict__ ub, const float* __restrict__ vb,
    float* __restrict__ ut, float* __restrict__ dt) {
  int idx = blockIdx.x * 256 + threadIdx.x;
  const int NU = kB * kS * kH;  // 65536
  if (idx < NU) {
    int h = idx & 15, bz = idx >> 4;
    int b = bz >> 8, z = bz & 255;
    const bf16x8* kp = (const bf16x8*)(QKVR + (size_t)bz * 4096 + 3072 + h * 64);
    const float* up = ub + h * 64;
    float a = 0.f;
#pragma unroll
    for (int i = 0; i < 8; ++i) {
      bf16x8 c = kp[i];
#pragma unroll
      for (int j = 0; j < 8; ++j) a += bf2f((u16)c[j]) * up[i * 8 + j];
    }
    ut[((b << 4) + h) * 256 + z] = a;
  } else if (idx < NU + kH * 256) {
    int j = idx - NU;
    int h = j >> 8, p = j & 255;
    const bf16x8* rp = (const bf16x8*)(RPR + (size_t)p * 1024 + h * 64);
    const float* vp = vb + h * 64;
    float a = 0.f;
#pragma unroll
    for (int i = 0; i < 8; ++i) {
      bf16x8 c = rp[i];
#pragma unroll
      for (int jj = 0; jj < 8; ++jj) a += bf2f((u16)c[jj]) * vp[i * 8 + jj];
    }
    dt[j] = a;
  }
}

// ---------------- fused MFMA attention (z-split across waves) ----------------
// Block = (b, h, 64-row s-tile). Each wave holds Q A-frags for all 4 row-tiles;
// QK/QR tile tasks are split across waves (disjoint Sc cells -> race-free).
__global__ __launch_bounds__(256) void attn_k(
    const u16* __restrict__ QKVR, const u16* __restrict__ RPK,
    const u16* __restrict__ Vt, const float* __restrict__ ut,
    const float* __restrict__ dt, u16* __restrict__ vw) {
  __shared__ float Sc[64][258];   // 66 KB
  __shared__ float Ut[256];
  __shared__ float Dt[256];

  const int blk = blockIdx.x;
  const int st = 3 - (blk & 3);   // heavy tiles first
  const int h  = (blk >> 2) & 15;
  const int b  = blk >> 6;
  const int s0 = st * 64;

  const int t = threadIdx.x, w = t >> 6, l = t & 63;
  const int l15 = l & 15, quad = l >> 4;

  // stage ut/dt rows for this (b,h)
  Ut[t] = ut[((b << 4) + h) * 256 + t];
  Dt[t] = dt[(h << 8) + t];

  // Q A-fragments for all 4 row-tiles
  bf16x8 qa[4][2];
#pragma unroll
  for (int rt = 0; rt < 4; ++rt) {
    const u16* qp = QKVR + (size_t)(b * 256 + s0 + rt * 16 + l15) * 4096 + h * 64 + quad * 8;
    qa[rt][0] = *(const bf16x8*)qp;
    qa[rt][1] = *(const bf16x8*)(qp + 32);
  }
  __syncthreads();

  // ---- QK^T + u_term: z-tiles split across waves ----
  const int zTiles = (s0 + 64) >> 4;  // 4*(st+1)
  for (int zt = w; zt < zTiles; zt += 4) {
    const int z0 = zt << 4;
    const u16* kp = QKVR + (size_t)(b * 256 + z0 + l15) * 4096 + 1024 + h * 64 + quad * 8;
    bf16x8 kb0 = *(const bf16x8*)kp;
    bf16x8 kb1 = *(const bf16x8*)(kp + 32);
    float u = Ut[z0 + l15];
    int rt0 = zt - (st << 2);
    if (rt0 < 0) rt0 = 0;
    for (int rt = rt0; rt < 4; ++rt) {
      floatx4 acc = {};
      acc = MFMA16(qa[rt][0], kb0, acc);
      acc = MFMA16(qa[rt][1], kb1, acc);
#pragma unroll
      for (int r = 0; r < 4; ++r)
        Sc[rt * 16 + quad * 4 + r][z0 + l15] = acc[r] + u;
    }
  }
  __syncthreads();

  // ---- QR: q_s . RPK[p] scatter-added into Sc[s][p+s-255]; tasks round-robin ----
  {
    int cnt = 0;
    for (int rt = 0; rt < 4; ++rt) {
      const int rB = s0 + rt * 16;
      const int nj = (st << 2) + rt + 1;
      for (int j = 0; j < nj; ++j, ++cnt) {
        if ((cnt & 3) != w) continue;
        const int p0 = 240 - rB + (j << 4);
        const u16* rp = RPK + (size_t)(p0 + l15) * 1024 + h * 64 + quad * 8;
        bf16x8 rb0 = *(const bf16x8*)rp;
        bf16x8 rb1 = *(const bf16x8*)(rp + 32);
        floatx4 acc = {};
        acc = MFMA16(qa[rt][0], rb0, acc);
        acc = MFMA16(qa[rt][1], rb1, acc);
        float dv = Dt[p0 + l15];
#pragma unroll
        for (int r = 0; r < 4; ++r) {
          int ro = quad * 4 + r;
          int z = p0 + l15 + rB + ro - 255;
          if (z >= 0) Sc[rt * 16 + ro][z] += acc[r] + dv;
        }
      }
    }
  }
  __syncthreads();

  // ---- per-wave strip: causal softmax (unnormalized) ----
  const int sB = s0 + w * 16;
  const int myrow = w * 16;
  const int zPV = ((sB + 16 + 31) >> 5) << 5;
  float sinv;
  {
    const int sr = l >> 2, c4 = l & 3;
    const int s = sB + sr;
    float m = -1e30f;
    for (int z = c4; z <= s; z += 4) m = fmaxf(m, Sc[myrow + sr][z]);
    m = fmaxf(m, __shfl_xor(m, 1));
    m = fmaxf(m, __shfl_xor(m, 2));
    m *= kScale;
    float sum = 0.f;
    for (int z = c4; z < zPV; z += 4) {
      float e = 0.f;
      if (z <= s) {
        e = __expf(Sc[myrow + sr][z] * kScale - m);
        sum += e;
      }
      Sc[myrow + sr][z] = e;
    }
    sum += __shfl_xor(sum, 1);
    sum += __shfl_xor(sum, 2);
    sinv = 1.f / sum;
  }

  // ---- PV: O[s,d] = sum_z P[s,z] * V[z,d] ----
  floatx4 oacc[4] = {};
  for (int kc = 0; kc < (zPV >> 5); ++kc) {
    const float* prow = &Sc[myrow + l15][kc * 32 + quad * 8];
    floatx4 p0 = *(const floatx4*)prow;
    floatx4 p1 = *(const floatx4*)(prow + 4);
    bf16x8 pa;
    pa[0] = (short)f2bf(p0[0]); pa[1] = (short)f2bf(p0[1]);
    pa[2] = (short)f2bf(p0[2]); pa[3] = (short)f2bf(p0[3]);
    pa[4] = (short)f2bf(p1[0]); pa[5] = (short)f2bf(p1[1]);
    pa[6] = (short)f2bf(p1[2]); pa[7] = (short)f2bf(p1[3]);
#pragma unroll
    for (int nt = 0; nt < 4; ++nt) {
      const u16* vp = Vt + (size_t)b * 262144 +
                      (size_t)(h * 64 + nt * 16 + l15) * 256 + kc * 32 + quad * 8;
      bf16x8 vbf = *(const bf16x8*)vp;
      oacc[nt] = MFMA16(pa, vbf, oacc[nt]);
    }
  }

  // ---- epilogue: normalize (rinv via shuffle), cast bf16, store ----
#pragma unroll
  for (int r = 0; r < 4; ++r) {
    float ivr = __shfl(sinv, (quad << 4) + (r << 2));
    int srow = sB + quad * 4 + r;
#pragma unroll
    for (int nt = 0; nt < 4; ++nt) {
      float val = oacc[nt][r] * ivr;
      vw[(size_t)(b * 256 + srow) * 1024 + h * 64 + nt * 16 + l15] = f2bf(val);
    }
  }
}

extern "C" void kernel_launch(void* const* d_in, const int* in_sizes, int n_in,
                              void* d_out, int out_size, void* d_ws, size_t ws_size,
                              hipStream_t stream) {
  const float* x  = (const float*)d_in[0];
  const float* Wq = (const float*)d_in[1];
  const float* bq = (const float*)d_in[2];
  const float* Wk = (const float*)d_in[3];
  const float* bk = (const float*)d_in[4];
  const float* Wv = (const float*)d_in[5];
  const float* bv = (const float*)d_in[6];
  const float* Wr = (const float*)d_in[7];
  const float* br = (const float*)d_in[8];
  const float* ub = (const float*)d_in[9];
  const float* vb = (const float*)d_in[10];
  const float* Wo = (const float*)d_in[11];
  const float* bo = (const float*)d_in[12];
  float* out = (float*)d_out;

  char* base = (char*)d_ws;
  size_t off = 0;
  auto alloc = [&](size_t bytes) {
    void* p = base + off;
    off += (bytes + 255) & ~(size_t)255;
    return p;
  };

  u16*   Tt    = (u16*)alloc((size_t)256 * 1024 * 2);
  u16*   xb    = (u16*)alloc((size_t)4096 * 1024 * 2);
  u16*   W4b   = (u16*)alloc((size_t)4096 * 1024 * 2);
  u16*   Wob   = (u16*)alloc((size_t)1024 * 1024 * 2);
  float* b4    = (float*)alloc((size_t)4096 * 4);
  u16*   QKVRb = (u16*)alloc((size_t)4096 * 4096 * 2);
  u16*   RPKb  = (u16*)alloc((size_t)256 * 1024 * 2);
  u16*   RPRb  = (u16*)alloc((size_t)256 * 1024 * 2);
  u16*   Vt    = (u16*)alloc((size_t)16 * 1024 * 256 * 2);
  float* ut    = (float*)alloc((size_t)65536 * 4);
  float* dtb   = (float*)alloc((size_t)16 * 256 * 4);
  u16*   vwb   = (u16*)alloc((size_t)4096 * 1024 * 2);

  make_table_k<<<dim3(1024), dim3(256), 0, stream>>>(Tt);
  pack_k<<<dim3(9220), dim3(256), 0, stream>>>(x, Wq, Wk, Wv, Wr, Wo, bq, bk, bv, br,
                                               xb, W4b, Wob, b4);

  // fused Q|K|V|KR projection: 4096 x 4096 x 1024
  gemm_k<1><<<dim3(32, 32), dim3(256), 0, stream>>>(xb, W4b, b4, QKVRb, 4096, 4096, 1024);
  // rel-pos projections (only p<256 survives the causal mask): 256 x 1024 x 1024
  gemm_k<1><<<dim3(8, 2), dim3(256), 0, stream>>>(Tt, W4b + (size_t)1024 * 1024,
                                                  b4 + 1024, RPKb, 256, 1024, 1024);
  gemm_k<1><<<dim3(8, 2), dim3(256), 0, stream>>>(Tt, W4b + (size_t)3072 * 1024,
                                                  b4 + 3072, RPRb, 256, 1024, 1024);

  transpose_v_k<<<dim3(4096), dim3(256), 0, stream>>>(QKVRb, Vt);
  bias_terms_k<<<dim3(272), dim3(256), 0, stream>>>(QKVRb, RPRb, ub, vb, ut, dtb);

  attn_k<<<dim3(1024), dim3(256), 0, stream>>>(QKVRb, RPKb, Vt, ut, dtb, vwb);

  // output projection: 4096 x 1024 x 1024, fp32 out
  gemm_k<0><<<dim3(8, 32), dim3(256), 0, stream>>>(vwb, Wob, bo, out, 4096, 1024, 1024);
}

// Round 4
// 278.825 us; speedup vs baseline: 1.6496x; 1.6496x over previous
//
#include <hip/hip_runtime.h>
#include <math.h>

constexpr int kB  = 16;
constexpr int kS  = 256;
constexpr int kD  = 1024;
constexpr int kH  = 16;
constexpr float kScale = 0.125f;  // 1/sqrt(64)

using bf16x8  = __attribute__((ext_vector_type(8))) short;
using floatx4 = __attribute__((ext_vector_type(4))) float;
typedef unsigned short u16;

__device__ __forceinline__ u16 f2bf(float x) {
  union { float f; unsigned u; } v; v.f = x;
  unsigned r = v.u + 0x7fffu + ((v.u >> 16) & 1u);
  return (u16)(r >> 16);
}
__device__ __forceinline__ float bf2f(u16 h) {
  union { unsigned u; float f; } v; v.u = ((unsigned)h) << 16;
  return v.f;
}

#define MFMA16(a, b, c) __builtin_amdgcn_mfma_f32_16x16x32_bf16((a), (b), (c), 0, 0, 0)
#define GLL16(gp, lp)                                                        \
  __builtin_amdgcn_global_load_lds(                                          \
      (const __attribute__((address_space(1))) unsigned int*)(gp),           \
      (__attribute__((address_space(3))) unsigned int*)(lp), 16, 0, 0)

// ---------------- sinusoid table rows: p in [0,256), pos = p-255, bf16 out --------
__global__ __launch_bounds__(256) void make_table_k(u16* __restrict__ T) {
  int idx = blockIdx.x * 256 + threadIdx.x;  // < 256*1024
  int p = idx >> 10;
  int i = idx & 1023;
  float ex = (float)(2 * (i / 2)) * (1.0f / 1024.0f);
  float scale = exp2f(ex * -13.287712379549449f);  // 10000^-ex
  float angle = (float)(p - 255) * scale;
  float v = (i & 1) ? cosf(angle) : sinf(angle);
  T[idx] = f2bf(v);
}

// ---------------- cast/pack (x4 vectorized) ----------------
__global__ __launch_bounds__(256) void pack_k(
    const float* __restrict__ x, const float* __restrict__ Wq,
    const float* __restrict__ Wk, const float* __restrict__ Wv,
    const float* __restrict__ Wr, const float* __restrict__ Wo,
    const float* __restrict__ bq, const float* __restrict__ bk,
    const float* __restrict__ bv, const float* __restrict__ br,
    u16* __restrict__ xb, u16* __restrict__ W4b, u16* __restrict__ Wob,
    float* __restrict__ b4) {
  size_t i = ((size_t)blockIdx.x * 256 + threadIdx.x) * 4;
  const size_t NX = (size_t)4194304, NW = (size_t)1048576;
  const float* src;
  u16* dst;
  size_t o;
  if (i < NX) {
    src = x; dst = xb; o = i;
  } else if (i < NX + 4 * NW) {
    size_t j = i - NX;
    int sel = (int)(j >> 20);
    o = j & (NW - 1);
    src = sel == 0 ? Wq : sel == 1 ? Wk : sel == 2 ? Wv : Wr;
    dst = W4b + (size_t)sel * NW;
  } else if (i < NX + 5 * NW) {
    o = i - NX - 4 * NW;
    src = Wo; dst = Wob;
  } else if (i < NX + 5 * NW + 4096) {
    size_t j = i - NX - 5 * NW;
    int sel = (int)(j >> 10);
    o = j & 1023;
    src = sel == 0 ? bq : sel == 1 ? bk : sel == 2 ? bv : br;
    *reinterpret_cast<float4*>(b4 + j) = *reinterpret_cast<const float4*>(src + o);
    return;
  } else {
    return;
  }
  float4 v = *reinterpret_cast<const float4*>(src + o);
  ushort4 r;
  r.x = f2bf(v.x); r.y = f2bf(v.y); r.z = f2bf(v.z); r.w = f2bf(v.w);
  *reinterpret_cast<ushort4*>(dst + o) = r;
}

// ---------------- bf16 MFMA GEMM: C = A @ W^T + bias ----------------
template <int OUT_BF16>
__global__ __launch_bounds__(256) void gemm_k(
    const u16* __restrict__ A, const u16* __restrict__ W,
    const float* __restrict__ bias, void* __restrict__ Cv,
    int M, int N, int K) {
  __shared__ u16 Alds[128 * 64];
  __shared__ u16 Blds[128 * 64];
  const int bm = blockIdx.y * 128, bn = blockIdx.x * 128;
  const int t = threadIdx.x, w = t >> 6, l = t & 63;
  const int l15 = l & 15, quad = l >> 4;
  const int wm = w >> 1, wn = w & 1;
  const int lrow8 = l >> 3;
  const int kslot = l & 7;

  floatx4 acc[4][4] = {};

  for (int k0 = 0; k0 < K; k0 += 64) {
#pragma unroll
    for (int sg = 0; sg < 4; ++sg) {
      int mrow = sg * 32 + w * 8 + lrow8;
      int gk = (kslot ^ (mrow & 7)) << 3;
      const u16* gpa = A + (size_t)(bm + mrow) * K + k0 + gk;
      const u16* gpb = W + (size_t)(bn + mrow) * K + k0 + gk;
      u16* lpa = Alds + (sg * 32 + w * 8) * 64;
      u16* lpb = Blds + (sg * 32 + w * 8) * 64;
      GLL16(gpa, lpa);
      GLL16(gpb, lpb);
    }
    __syncthreads();
#pragma unroll
    for (int c = 0; c < 2; ++c) {
      bf16x8 af[4], bf[4];
#pragma unroll
      for (int mi = 0; mi < 4; ++mi) {
        int am = wm * 64 + mi * 16 + l15;
        af[mi] = *(const bf16x8*)(Alds + am * 64 + (((c * 4 + quad) ^ (am & 7)) << 3));
      }
#pragma unroll
      for (int ni = 0; ni < 4; ++ni) {
        int an = wn * 64 + ni * 16 + l15;
        bf[ni] = *(const bf16x8*)(Blds + an * 64 + (((c * 4 + quad) ^ (an & 7)) << 3));
      }
#pragma unroll
      for (int mi = 0; mi < 4; ++mi)
#pragma unroll
        for (int ni = 0; ni < 4; ++ni)
          acc[mi][ni] = MFMA16(af[mi], bf[ni], acc[mi][ni]);
    }
    __syncthreads();
  }

#pragma unroll
  for (int ni = 0; ni < 4; ++ni) {
    int col = bn + wn * 64 + ni * 16 + l15;
    float bv = bias[col];
#pragma unroll
    for (int mi = 0; mi < 4; ++mi) {
      int mrow = bm + wm * 64 + mi * 16 + quad * 4;
#pragma unroll
      for (int r = 0; r < 4; ++r) {
        float v = acc[mi][ni][r] + bv;
        if (OUT_BF16)
          ((u16*)Cv)[(size_t)(mrow + r) * N + col] = f2bf(v);
        else
          ((float*)Cv)[(size_t)(mrow + r) * N + col] = v;
      }
    }
  }
}

// ---------------- V transpose: Vt[b][d][z] <- QKVR[(b*S+z)*4096 + 2048 + d] -------
__global__ __launch_bounds__(256) void transpose_v_k(const u16* __restrict__ Q4,
                                                     u16* __restrict__ Vt) {
  __shared__ u16 tile[32][36];
  int blk = blockIdx.x;
  int dt6 = blk & 31;
  int zt  = (blk >> 5) & 7;
  int b   = blk >> 8;
  int t = threadIdx.x;
  int r = t >> 3, cc = t & 7;
  const u16* gp = Q4 + (size_t)(b * 256 + zt * 32 + r) * 4096 + 2048 + dt6 * 32 + cc * 4;
  ushort4 vv = *(const ushort4*)gp;
  tile[r][cc * 4 + 0] = vv.x;
  tile[r][cc * 4 + 1] = vv.y;
  tile[r][cc * 4 + 2] = vv.z;
  tile[r][cc * 4 + 3] = vv.w;
  __syncthreads();
  ushort4 o;
  o.x = tile[cc * 4 + 0][r];
  o.y = tile[cc * 4 + 1][r];
  o.z = tile[cc * 4 + 2][r];
  o.w = tile[cc * 4 + 3][r];
  u16* op = Vt + (size_t)b * 262144 + (size_t)(dt6 * 32 + r) * 256 + zt * 32 + cc * 4;
  *(ushort4*)op = o;
}

// ---------------- small bias-dot terms ----------------
// ut[(b*H+h)*256 + z] = u_bias[h] . KR[b,z,h,:]
// dt[h*256 + p]       = v_bias[h] . RPR[p,h,:]
__global__ __launch_bounds__(256) void bias_terms_k(
    const u16* __restrict__ QKVR, const u16* __restrict__ RPR,
    const float* __restrict__ ub, const float* __restrict__ vb,
    float* __restrict__ ut, float* __restrict__ dt) {
  int idx = blockIdx.x * 256 + threadIdx.x;
  const int NU = kB * kS * kH;  // 65536
  if (idx < NU) {
    int h = idx & 15, bz = idx >> 4;
    int b = bz >> 8, z = bz & 255;
    const bf16x8* kp = (const bf16x8*)(QKVR + (size_t)bz * 4096 + 3072 + h * 64);
    const float* up = ub + h * 64;
    float a = 0.f;
#pragma unroll
    for (int i = 0; i < 8; ++i) {
      bf16x8 c = kp[i];
#pragma unroll
      for (int j = 0; j < 8; ++j) a += bf2f((u16)c[j]) * up[i * 8 + j];
    }
    ut[((b << 4) + h) * 256 + z] = a;
  } else if (idx < NU + kH * 256) {
    int j = idx - NU;
    int h = j >> 8, p = j & 255;
    const bf16x8* rp = (const bf16x8*)(RPR + (size_t)p * 1024 + h * 64);
    const float* vp = vb + h * 64;
    float a = 0.f;
#pragma unroll
    for (int i = 0; i < 8; ++i) {
      bf16x8 c = rp[i];
#pragma unroll
      for (int jj = 0; jj < 8; ++jj) a += bf2f((u16)c[jj]) * vp[i * 8 + jj];
    }
    dt[j] = a;
  }
}

// ---------------- fused MFMA attention (z-split, compile-time frag indexing) -----
// Block = (b, h, 64-row s-tile). Each wave holds Q A-frags for all 4 row-tiles;
// QK/QR tile tasks are split across waves (disjoint Sc cells -> race-free).
// NOTE: every qa[] index must be a literal constant (round-3 lesson: runtime
// indexing lowers the frag array to scratch -> 14x VALU explosion).
__global__ __launch_bounds__(256) void attn_k(
    const u16* __restrict__ QKVR, const u16* __restrict__ RPK,
    const u16* __restrict__ Vt, const float* __restrict__ ut,
    const float* __restrict__ dt, u16* __restrict__ vw) {
  __shared__ float Sc[64][258];   // 66 KB
  __shared__ float Ut[256];
  __shared__ float Dt[256];

  const int blk = blockIdx.x;
  const int st = 3 - (blk & 3);   // heavy tiles first
  const int h  = (blk >> 2) & 15;
  const int b  = blk >> 6;
  const int s0 = st * 64;

  const int t = threadIdx.x, w = t >> 6, l = t & 63;
  const int l15 = l & 15, quad = l >> 4;

  // stage ut/dt rows for this (b,h)
  Ut[t] = ut[((b << 4) + h) * 256 + t];
  Dt[t] = dt[(h << 8) + t];

  // Q A-fragments for all 4 row-tiles (constant-indexed everywhere)
  bf16x8 qa[4][2];
#pragma unroll
  for (int rt = 0; rt < 4; ++rt) {
    const u16* qp = QKVR + (size_t)(b * 256 + s0 + rt * 16 + l15) * 4096 + h * 64 + quad * 8;
    qa[rt][0] = *(const bf16x8*)qp;
    qa[rt][1] = *(const bf16x8*)(qp + 32);
  }
  __syncthreads();

  // ---- QK^T + u_term: z-tiles split across waves ----
  const int zTiles = (s0 + 64) >> 4;  // 4*(st+1)
  for (int zt = w; zt < zTiles; zt += 4) {
    const int z0 = zt << 4;
    const u16* kp = QKVR + (size_t)(b * 256 + z0 + l15) * 4096 + 1024 + h * 64 + quad * 8;
    bf16x8 kb0 = *(const bf16x8*)kp;
    bf16x8 kb1 = *(const bf16x8*)(kp + 32);
    float u = Ut[z0 + l15];
    const int rtmin = zt - (st << 2);  // wave-uniform
#pragma unroll
    for (int rt = 0; rt < 4; ++rt) {
      if (rt >= rtmin) {               // uniform branch, constant rt
        floatx4 acc = {};
        acc = MFMA16(qa[rt][0], kb0, acc);
        acc = MFMA16(qa[rt][1], kb1, acc);
#pragma unroll
        for (int r = 0; r < 4; ++r)
          Sc[rt * 16 + quad * 4 + r][z0 + l15] = acc[r] + u;
      }
    }
  }
  __syncthreads();

  // ---- QR: q_s . RPK[p] scatter-added into Sc[s][p+s-255]; rt compile-time ----
  {
    int cnt = 0;
#pragma unroll
    for (int rt = 0; rt < 4; ++rt) {
      const int rB = s0 + rt * 16;
      const int nj = (st << 2) + rt + 1;
      for (int j = 0; j < nj; ++j, ++cnt) {
        if ((cnt & 3) != w) continue;  // wave-uniform
        const int p0 = 240 - rB + (j << 4);
        const u16* rp = RPK + (size_t)(p0 + l15) * 1024 + h * 64 + quad * 8;
        bf16x8 rb0 = *(const bf16x8*)rp;
        bf16x8 rb1 = *(const bf16x8*)(rp + 32);
        floatx4 acc = {};
        acc = MFMA16(qa[rt][0], rb0, acc);
        acc = MFMA16(qa[rt][1], rb1, acc);
        float dv = Dt[p0 + l15];
#pragma unroll
        for (int r = 0; r < 4; ++r) {
          int ro = quad * 4 + r;
          int z = p0 + l15 + rB + ro - 255;
          if (z >= 0) Sc[rt * 16 + ro][z] += acc[r] + dv;
        }
      }
    }
  }
  __syncthreads();

  // ---- per-wave strip: causal softmax (unnormalized) ----
  const int sB = s0 + w * 16;
  const int myrow = w * 16;
  const int zPV = ((sB + 16 + 31) >> 5) << 5;
  float sinv;
  {
    const int sr = l >> 2, c4 = l & 3;
    const int s = sB + sr;
    float m = -1e30f;
    for (int z = c4; z <= s; z += 4) m = fmaxf(m, Sc[myrow + sr][z]);
    m = fmaxf(m, __shfl_xor(m, 1));
    m = fmaxf(m, __shfl_xor(m, 2));
    m *= kScale;
    float sum = 0.f;
    for (int z = c4; z < zPV; z += 4) {
      float e = 0.f;
      if (z <= s) {
        e = __expf(Sc[myrow + sr][z] * kScale - m);
        sum += e;
      }
      Sc[myrow + sr][z] = e;
    }
    sum += __shfl_xor(sum, 1);
    sum += __shfl_xor(sum, 2);
    sinv = 1.f / sum;
  }

  // ---- PV: O[s,d] = sum_z P[s,z] * V[z,d] ----
  floatx4 oacc[4] = {};
  for (int kc = 0; kc < (zPV >> 5); ++kc) {
    const float* prow = &Sc[myrow + l15][kc * 32 + quad * 8];
    floatx4 p0 = *(const floatx4*)prow;
    floatx4 p1 = *(const floatx4*)(prow + 4);
    bf16x8 pa;
    pa[0] = (short)f2bf(p0[0]); pa[1] = (short)f2bf(p0[1]);
    pa[2] = (short)f2bf(p0[2]); pa[3] = (short)f2bf(p0[3]);
    pa[4] = (short)f2bf(p1[0]); pa[5] = (short)f2bf(p1[1]);
    pa[6] = (short)f2bf(p1[2]); pa[7] = (short)f2bf(p1[3]);
#pragma unroll
    for (int nt = 0; nt < 4; ++nt) {
      const u16* vp = Vt + (size_t)b * 262144 +
                      (size_t)(h * 64 + nt * 16 + l15) * 256 + kc * 32 + quad * 8;
      bf16x8 vbf = *(const bf16x8*)vp;
      oacc[nt] = MFMA16(pa, vbf, oacc[nt]);
    }
  }

  // ---- epilogue: normalize (rinv via shuffle), cast bf16, store ----
#pragma unroll
  for (int r = 0; r < 4; ++r) {
    float ivr = __shfl(sinv, (quad << 4) + (r << 2));
    int srow = sB + quad * 4 + r;
#pragma unroll
    for (int nt = 0; nt < 4; ++nt) {
      float val = oacc[nt][r] * ivr;
      vw[(size_t)(b * 256 + srow) * 1024 + h * 64 + nt * 16 + l15] = f2bf(val);
    }
  }
}

extern "C" void kernel_launch(void* const* d_in, const int* in_sizes, int n_in,
                              void* d_out, int out_size, void* d_ws, size_t ws_size,
                              hipStream_t stream) {
  const float* x  = (const float*)d_in[0];
  const float* Wq = (const float*)d_in[1];
  const float* bq = (const float*)d_in[2];
  const float* Wk = (const float*)d_in[3];
  const float* bk = (const float*)d_in[4];
  const float* Wv = (const float*)d_in[5];
  const float* bv = (const float*)d_in[6];
  const float* Wr = (const float*)d_in[7];
  const float* br = (const float*)d_in[8];
  const float* ub = (const float*)d_in[9];
  const float* vb = (const float*)d_in[10];
  const float* Wo = (const float*)d_in[11];
  const float* bo = (const float*)d_in[12];
  float* out = (float*)d_out;

  char* base = (char*)d_ws;
  size_t off = 0;
  auto alloc = [&](size_t bytes) {
    void* p = base + off;
    off += (bytes + 255) & ~(size_t)255;
    return p;
  };

  u16*   Tt    = (u16*)alloc((size_t)256 * 1024 * 2);
  u16*   xb    = (u16*)alloc((size_t)4096 * 1024 * 2);
  u16*   W4b   = (u16*)alloc((size_t)4096 * 1024 * 2);
  u16*   Wob   = (u16*)alloc((size_t)1024 * 1024 * 2);
  float* b4    = (float*)alloc((size_t)4096 * 4);
  u16*   QKVRb = (u16*)alloc((size_t)4096 * 4096 * 2);
  u16*   RPKb  = (u16*)alloc((size_t)256 * 1024 * 2);
  u16*   RPRb  = (u16*)alloc((size_t)256 * 1024 * 2);
  u16*   Vt    = (u16*)alloc((size_t)16 * 1024 * 256 * 2);
  float* ut    = (float*)alloc((size_t)65536 * 4);
  float* dtb   = (float*)alloc((size_t)16 * 256 * 4);
  u16*   vwb   = (u16*)alloc((size_t)4096 * 1024 * 2);

  make_table_k<<<dim3(1024), dim3(256), 0, stream>>>(Tt);
  pack_k<<<dim3(9220), dim3(256), 0, stream>>>(x, Wq, Wk, Wv, Wr, Wo, bq, bk, bv, br,
                                               xb, W4b, Wob, b4);

  // fused Q|K|V|KR projection: 4096 x 4096 x 1024
  gemm_k<1><<<dim3(32, 32), dim3(256), 0, stream>>>(xb, W4b, b4, QKVRb, 4096, 4096, 1024);
  // rel-pos projections (only p<256 survives the causal mask): 256 x 1024 x 1024
  gemm_k<1><<<dim3(8, 2), dim3(256), 0, stream>>>(Tt, W4b + (size_t)1024 * 1024,
                                                  b4 + 1024, RPKb, 256, 1024, 1024);
  gemm_k<1><<<dim3(8, 2), dim3(256), 0, stream>>>(Tt, W4b + (size_t)3072 * 1024,
                                                  b4 + 3072, RPRb, 256, 1024, 1024);

  transpose_v_k<<<dim3(4096), dim3(256), 0, stream>>>(QKVRb, Vt);
  bias_terms_k<<<dim3(272), dim3(256), 0, stream>>>(QKVRb, RPRb, ub, vb, ut, dtb);

  attn_k<<<dim3(1024), dim3(256), 0, stream>>>(QKVRb, RPKb, Vt, ut, dtb, vwb);

  // output projection: 4096 x 1024 x 1024, fp32 out
  gemm_k<0><<<dim3(8, 32), dim3(256), 0, stream>>>(vwb, Wob, bo, out, 4096, 1024, 1024);
}

// Round 5
// 274.191 us; speedup vs baseline: 1.6775x; 1.0169x over previous
//
#include <hip/hip_runtime.h>
#include <math.h>

constexpr int kB  = 16;
constexpr int kS  = 256;
constexpr int kD  = 1024;
constexpr int kH  = 16;
constexpr float kScale = 0.125f;  // 1/sqrt(64)

using bf16x8  = __attribute__((ext_vector_type(8))) short;
using floatx4 = __attribute__((ext_vector_type(4))) float;
typedef unsigned short u16;

__device__ __forceinline__ u16 f2bf(float x) {
  union { float f; unsigned u; } v; v.f = x;
  unsigned r = v.u + 0x7fffu + ((v.u >> 16) & 1u);
  return (u16)(r >> 16);
}
__device__ __forceinline__ float bf2f(u16 h) {
  union { unsigned u; float f; } v; v.u = ((unsigned)h) << 16;
  return v.f;
}

#define MFMA16(a, b, c) __builtin_amdgcn_mfma_f32_16x16x32_bf16((a), (b), (c), 0, 0, 0)
#define GLL16(gp, lp)                                                        \
  __builtin_amdgcn_global_load_lds(                                          \
      (const __attribute__((address_space(1))) unsigned int*)(gp),           \
      (__attribute__((address_space(3))) unsigned int*)(lp), 16, 0, 0)

// ---------------- sinusoid table rows: p in [0,256), pos = p-255, bf16 out --------
__global__ __launch_bounds__(256) void make_table_k(u16* __restrict__ T) {
  int idx = blockIdx.x * 256 + threadIdx.x;  // < 256*1024
  int p = idx >> 10;
  int i = idx & 1023;
  float ex = (float)(2 * (i / 2)) * (1.0f / 1024.0f);
  float scale = exp2f(ex * -13.287712379549449f);  // 10000^-ex
  float angle = (float)(p - 255) * scale;
  float v = (i & 1) ? cosf(angle) : sinf(angle);
  T[idx] = f2bf(v);
}

// ---------------- cast/pack (x4 vectorized) ----------------
__global__ __launch_bounds__(256) void pack_k(
    const float* __restrict__ x, const float* __restrict__ Wq,
    const float* __restrict__ Wk, const float* __restrict__ Wv,
    const float* __restrict__ Wr, const float* __restrict__ Wo,
    const float* __restrict__ bq, const float* __restrict__ bk,
    const float* __restrict__ bv, const float* __restrict__ br,
    u16* __restrict__ xb, u16* __restrict__ W4b, u16* __restrict__ Wob,
    float* __restrict__ b4) {
  size_t i = ((size_t)blockIdx.x * 256 + threadIdx.x) * 4;
  const size_t NX = (size_t)4194304, NW = (size_t)1048576;
  const float* src;
  u16* dst;
  size_t o;
  if (i < NX) {
    src = x; dst = xb; o = i;
  } else if (i < NX + 4 * NW) {
    size_t j = i - NX;
    int sel = (int)(j >> 20);
    o = j & (NW - 1);
    src = sel == 0 ? Wq : sel == 1 ? Wk : sel == 2 ? Wv : Wr;
    dst = W4b + (size_t)sel * NW;
  } else if (i < NX + 5 * NW) {
    o = i - NX - 4 * NW;
    src = Wo; dst = Wob;
  } else if (i < NX + 5 * NW + 4096) {
    size_t j = i - NX - 5 * NW;
    int sel = (int)(j >> 10);
    o = j & 1023;
    src = sel == 0 ? bq : sel == 1 ? bk : sel == 2 ? bv : br;
    *reinterpret_cast<float4*>(b4 + j) = *reinterpret_cast<const float4*>(src + o);
    return;
  } else {
    return;
  }
  float4 v = *reinterpret_cast<const float4*>(src + o);
  ushort4 r;
  r.x = f2bf(v.x); r.y = f2bf(v.y); r.z = f2bf(v.z); r.w = f2bf(v.w);
  *reinterpret_cast<ushort4*>(dst + o) = r;
}

// ---------------- bf16 MFMA GEMM: C = A @ W^T + bias ----------------
template <int OUT_BF16>
__global__ __launch_bounds__(256) void gemm_k(
    const u16* __restrict__ A, const u16* __restrict__ W,
    const float* __restrict__ bias, void* __restrict__ Cv,
    int M, int N, int K) {
  __shared__ u16 Alds[128 * 64];
  __shared__ u16 Blds[128 * 64];
  const int bm = blockIdx.y * 128, bn = blockIdx.x * 128;
  const int t = threadIdx.x, w = t >> 6, l = t & 63;
  const int l15 = l & 15, quad = l >> 4;
  const int wm = w >> 1, wn = w & 1;
  const int lrow8 = l >> 3;
  const int kslot = l & 7;

  floatx4 acc[4][4] = {};

  for (int k0 = 0; k0 < K; k0 += 64) {
#pragma unroll
    for (int sg = 0; sg < 4; ++sg) {
      int mrow = sg * 32 + w * 8 + lrow8;
      int gk = (kslot ^ (mrow & 7)) << 3;
      const u16* gpa = A + (size_t)(bm + mrow) * K + k0 + gk;
      const u16* gpb = W + (size_t)(bn + mrow) * K + k0 + gk;
      u16* lpa = Alds + (sg * 32 + w * 8) * 64;
      u16* lpb = Blds + (sg * 32 + w * 8) * 64;
      GLL16(gpa, lpa);
      GLL16(gpb, lpb);
    }
    __syncthreads();
#pragma unroll
    for (int c = 0; c < 2; ++c) {
      bf16x8 af[4], bf[4];
#pragma unroll
      for (int mi = 0; mi < 4; ++mi) {
        int am = wm * 64 + mi * 16 + l15;
        af[mi] = *(const bf16x8*)(Alds + am * 64 + (((c * 4 + quad) ^ (am & 7)) << 3));
      }
#pragma unroll
      for (int ni = 0; ni < 4; ++ni) {
        int an = wn * 64 + ni * 16 + l15;
        bf[ni] = *(const bf16x8*)(Blds + an * 64 + (((c * 4 + quad) ^ (an & 7)) << 3));
      }
#pragma unroll
      for (int mi = 0; mi < 4; ++mi)
#pragma unroll
        for (int ni = 0; ni < 4; ++ni)
          acc[mi][ni] = MFMA16(af[mi], bf[ni], acc[mi][ni]);
    }
    __syncthreads();
  }

#pragma unroll
  for (int ni = 0; ni < 4; ++ni) {
    int col = bn + wn * 64 + ni * 16 + l15;
    float bv = bias[col];
#pragma unroll
    for (int mi = 0; mi < 4; ++mi) {
      int mrow = bm + wm * 64 + mi * 16 + quad * 4;
#pragma unroll
      for (int r = 0; r < 4; ++r) {
        float v = acc[mi][ni][r] + bv;
        if (OUT_BF16)
          ((u16*)Cv)[(size_t)(mrow + r) * N + col] = f2bf(v);
        else
          ((float*)Cv)[(size_t)(mrow + r) * N + col] = v;
      }
    }
  }
}

// ---------------- V transpose: Vt[b][d][z] <- QKVR[(b*S+z)*4096 + 2048 + d] -------
__global__ __launch_bounds__(256) void transpose_v_k(const u16* __restrict__ Q4,
                                                     u16* __restrict__ Vt) {
  __shared__ u16 tile[32][36];
  int blk = blockIdx.x;
  int dt6 = blk & 31;
  int zt  = (blk >> 5) & 7;
  int b   = blk >> 8;
  int t = threadIdx.x;
  int r = t >> 3, cc = t & 7;
  const u16* gp = Q4 + (size_t)(b * 256 + zt * 32 + r) * 4096 + 2048 + dt6 * 32 + cc * 4;
  ushort4 vv = *(const ushort4*)gp;
  tile[r][cc * 4 + 0] = vv.x;
  tile[r][cc * 4 + 1] = vv.y;
  tile[r][cc * 4 + 2] = vv.z;
  tile[r][cc * 4 + 3] = vv.w;
  __syncthreads();
  ushort4 o;
  o.x = tile[cc * 4 + 0][r];
  o.y = tile[cc * 4 + 1][r];
  o.z = tile[cc * 4 + 2][r];
  o.w = tile[cc * 4 + 3][r];
  u16* op = Vt + (size_t)b * 262144 + (size_t)(dt6 * 32 + r) * 256 + zt * 32 + cc * 4;
  *(ushort4*)op = o;
}

// ---------------- small bias-dot terms ----------------
// ut[(b*H+h)*256 + z] = u_bias[h] . KR[b,z,h,:]
// dt[h*256 + p]       = v_bias[h] . RPR[p,h,:]
__global__ __launch_bounds__(256) void bias_terms_k(
    const u16* __restrict__ QKVR, const u16* __restrict__ RPR,
    const float* __restrict__ ub, const float* __restrict__ vb,
    float* __restrict__ ut, float* __restrict__ dt) {
  int idx = blockIdx.x * 256 + threadIdx.x;
  const int NU = kB * kS * kH;  // 65536
  if (idx < NU) {
    int h = idx & 15, bz = idx >> 4;
    int b = bz >> 8, z = bz & 255;
    const bf16x8* kp = (const bf16x8*)(QKVR + (size_t)bz * 4096 + 3072 + h * 64);
    const float* up = ub + h * 64;
    float a = 0.f;
#pragma unroll
    for (int i = 0; i < 8; ++i) {
      bf16x8 c = kp[i];
#pragma unroll
      for (int j = 0; j < 8; ++j) a += bf2f((u16)c[j]) * up[i * 8 + j];
    }
    ut[((b << 4) + h) * 256 + z] = a;
  } else if (idx < NU + kH * 256) {
    int j = idx - NU;
    int h = j >> 8, p = j & 255;
    const bf16x8* rp = (const bf16x8*)(RPR + (size_t)p * 1024 + h * 64);
    const float* vp = vb + h * 64;
    float a = 0.f;
#pragma unroll
    for (int i = 0; i < 8; ++i) {
      bf16x8 c = rp[i];
#pragma unroll
      for (int jj = 0; jj < 8; ++jj) a += bf2f((u16)c[jj]) * vp[i * 8 + jj];
    }
    dt[j] = a;
  }
}

// ---------------- fused MFMA attention, 32-row s-tiles for occupancy ----------------
// Block = (b, h, 32-row s-tile); LDS ~35 KB -> 4 blocks/CU (16 waves/CU).
// QK/QR tile tasks split across 4 waves (disjoint Sc cells -> race-free).
// All frag-array indices are compile-time (round-3 lesson: runtime indexing
// lowers frag arrays to scratch -> VALU explosion).
__global__ __launch_bounds__(256, 4) void attn_k(
    const u16* __restrict__ QKVR, const u16* __restrict__ RPK,
    const u16* __restrict__ Vt, const float* __restrict__ ut,
    const float* __restrict__ dt, u16* __restrict__ vw) {
  __shared__ float Sc[32][258];   // 33 KB
  __shared__ float Ut[256];
  __shared__ float Dt[256];
  __shared__ float Rinv[32];

  const int blk = blockIdx.x;
  const int st = 7 - (blk & 7);   // heavy tiles first
  const int h  = (blk >> 3) & 15;
  const int b  = blk >> 7;
  const int s0 = st * 32;

  const int t = threadIdx.x, w = t >> 6, l = t & 63;
  const int l15 = l & 15, quad = l >> 4;

  // stage ut/dt rows for this (b,h)
  Ut[t] = ut[((b << 4) + h) * 256 + t];
  Dt[t] = dt[(h << 8) + t];

  // Q A-fragments for both row-tiles (constant-indexed everywhere)
  bf16x8 qa[2][2];
#pragma unroll
  for (int rt = 0; rt < 2; ++rt) {
    const u16* qp = QKVR + (size_t)(b * 256 + s0 + rt * 16 + l15) * 4096 + h * 64 + quad * 8;
    qa[rt][0] = *(const bf16x8*)qp;
    qa[rt][1] = *(const bf16x8*)(qp + 32);
  }
  __syncthreads();

  // ---- QK^T + u_term: z-tiles split across waves ----
  const int zTiles = (s0 + 32) >> 4;  // 2*(st+1)
  for (int zt = w; zt < zTiles; zt += 4) {
    const int z0 = zt << 4;
    const u16* kp = QKVR + (size_t)(b * 256 + z0 + l15) * 4096 + 1024 + h * 64 + quad * 8;
    bf16x8 kb0 = *(const bf16x8*)kp;
    bf16x8 kb1 = *(const bf16x8*)(kp + 32);
    float u = Ut[z0 + l15];
    const int rtmin = zt - (st << 1);  // wave-uniform
#pragma unroll
    for (int rt = 0; rt < 2; ++rt) {
      if (rt >= rtmin) {               // uniform branch, constant rt
        floatx4 acc = {};
        acc = MFMA16(qa[rt][0], kb0, acc);
        acc = MFMA16(qa[rt][1], kb1, acc);
#pragma unroll
        for (int r = 0; r < 4; ++r)
          Sc[rt * 16 + quad * 4 + r][z0 + l15] = acc[r] + u;
      }
    }
  }
  __syncthreads();

  // ---- QR: q_s . RPK[p] scatter-added into Sc[s][p+s-255]; rt compile-time ----
  {
    int cnt = 0;
#pragma unroll
    for (int rt = 0; rt < 2; ++rt) {
      const int rB = s0 + rt * 16;
      const int nj = (st << 1) + rt + 1;
      for (int j = 0; j < nj; ++j, ++cnt) {
        if ((cnt & 3) != w) continue;  // wave-uniform
        const int p0 = 240 - rB + (j << 4);
        const u16* rp = RPK + (size_t)(p0 + l15) * 1024 + h * 64 + quad * 8;
        bf16x8 rb0 = *(const bf16x8*)rp;
        bf16x8 rb1 = *(const bf16x8*)(rp + 32);
        floatx4 acc = {};
        acc = MFMA16(qa[rt][0], rb0, acc);
        acc = MFMA16(qa[rt][1], rb1, acc);
        float dv = Dt[p0 + l15];
#pragma unroll
        for (int r = 0; r < 4; ++r) {
          int ro = quad * 4 + r;
          int z = p0 + l15 + rB + ro - 255;
          if (z >= 0) Sc[rt * 16 + ro][z] += acc[r] + dv;
        }
      }
    }
  }
  __syncthreads();

  // ---- causal softmax: 8 rows/wave, 8 lanes/row (unnormalized; 1/sum in LDS) ----
  {
    const int row = w * 8 + (l >> 3);  // 0..31
    const int c8 = l & 7;
    const int s = s0 + row;
    const int zfill = ((s0 + ((row >> 4) + 1) * 16 + 31) >> 5) << 5;  // strip PV range
    float m = -1e30f;
    for (int z = c8; z <= s; z += 8) m = fmaxf(m, Sc[row][z]);
    m = fmaxf(m, __shfl_xor(m, 1));
    m = fmaxf(m, __shfl_xor(m, 2));
    m = fmaxf(m, __shfl_xor(m, 4));
    m *= kScale;
    float sum = 0.f;
    for (int z = c8; z < zfill; z += 8) {
      float e = 0.f;
      if (z <= s) {
        e = __expf(Sc[row][z] * kScale - m);
        sum += e;
      }
      Sc[row][z] = e;
    }
    sum += __shfl_xor(sum, 1);
    sum += __shfl_xor(sum, 2);
    sum += __shfl_xor(sum, 4);
    if (c8 == 0) Rinv[row] = 1.f / sum;
  }
  __syncthreads();

  // ---- PV: wave = (strip, nt-pair); O[s,d] = sum_z P[s,z] * V[z,d] ----
  const int strip = w >> 1;          // 0..1
  const int ntb = (w & 1) * 2;       // 0 or 2
  const int sB = s0 + strip * 16;
  const int kcN = (sB + 16 + 31) >> 5;
  floatx4 oacc[2] = {};
  for (int kc = 0; kc < kcN; ++kc) {
    const float* prow = &Sc[strip * 16 + l15][kc * 32 + quad * 8];
    float p0 = prow[0], p1 = prow[1], p2 = prow[2], p3 = prow[3];
    float p4 = prow[4], p5 = prow[5], p6 = prow[6], p7 = prow[7];
    bf16x8 pa;
    pa[0] = (short)f2bf(p0); pa[1] = (short)f2bf(p1);
    pa[2] = (short)f2bf(p2); pa[3] = (short)f2bf(p3);
    pa[4] = (short)f2bf(p4); pa[5] = (short)f2bf(p5);
    pa[6] = (short)f2bf(p6); pa[7] = (short)f2bf(p7);
#pragma unroll
    for (int nt = 0; nt < 2; ++nt) {
      const u16* vp = Vt + (size_t)b * 262144 +
                      (size_t)(h * 64 + (ntb + nt) * 16 + l15) * 256 + kc * 32 + quad * 8;
      bf16x8 vbf = *(const bf16x8*)vp;
      oacc[nt] = MFMA16(pa, vbf, oacc[nt]);
    }
  }

  // ---- epilogue: normalize, cast bf16, store ----
#pragma unroll
  for (int r = 0; r < 4; ++r) {
    float ivr = Rinv[strip * 16 + quad * 4 + r];
    int srow = sB + quad * 4 + r;
#pragma unroll
    for (int nt = 0; nt < 2; ++nt) {
      float val = oacc[nt][r] * ivr;
      vw[(size_t)(b * 256 + srow) * 1024 + h * 64 + (ntb + nt) * 16 + l15] = f2bf(val);
    }
  }
}

extern "C" void kernel_launch(void* const* d_in, const int* in_sizes, int n_in,
                              void* d_out, int out_size, void* d_ws, size_t ws_size,
                              hipStream_t stream) {
  const float* x  = (const float*)d_in[0];
  const float* Wq = (const float*)d_in[1];
  const float* bq = (const float*)d_in[2];
  const float* Wk = (const float*)d_in[3];
  const float* bk = (const float*)d_in[4];
  const float* Wv = (const float*)d_in[5];
  const float* bv = (const float*)d_in[6];
  const float* Wr = (const float*)d_in[7];
  const float* br = (const float*)d_in[8];
  const float* ub = (const float*)d_in[9];
  const float* vb = (const float*)d_in[10];
  const float* Wo = (const float*)d_in[11];
  const float* bo = (const float*)d_in[12];
  float* out = (float*)d_out;

  char* base = (char*)d_ws;
  size_t off = 0;
  auto alloc = [&](size_t bytes) {
    void* p = base + off;
    off += (bytes + 255) & ~(size_t)255;
    return p;
  };

  u16*   Tt    = (u16*)alloc((size_t)256 * 1024 * 2);
  u16*   xb    = (u16*)alloc((size_t)4096 * 1024 * 2);
  u16*   W4b   = (u16*)alloc((size_t)4096 * 1024 * 2);
  u16*   Wob   = (u16*)alloc((size_t)1024 * 1024 * 2);
  float* b4    = (float*)alloc((size_t)4096 * 4);
  u16*   QKVRb = (u16*)alloc((size_t)4096 * 4096 * 2);
  u16*   RPKb  = (u16*)alloc((size_t)256 * 1024 * 2);
  u16*   RPRb  = (u16*)alloc((size_t)256 * 1024 * 2);
  u16*   Vt    = (u16*)alloc((size_t)16 * 1024 * 256 * 2);
  float* ut    = (float*)alloc((size_t)65536 * 4);
  float* dtb   = (float*)alloc((size_t)16 * 256 * 4);
  u16*   vwb   = (u16*)alloc((size_t)4096 * 1024 * 2);

  make_table_k<<<dim3(1024), dim3(256), 0, stream>>>(Tt);
  pack_k<<<dim3(9220), dim3(256), 0, stream>>>(x, Wq, Wk, Wv, Wr, Wo, bq, bk, bv, br,
                                               xb, W4b, Wob, b4);

  // fused Q|K|V|KR projection: 4096 x 4096 x 1024
  gemm_k<1><<<dim3(32, 32), dim3(256), 0, stream>>>(xb, W4b, b4, QKVRb, 4096, 4096, 1024);
  // rel-pos projections (only p<256 survives the causal mask): 256 x 1024 x 1024
  gemm_k<1><<<dim3(8, 2), dim3(256), 0, stream>>>(Tt, W4b + (size_t)1024 * 1024,
                                                  b4 + 1024, RPKb, 256, 1024, 1024);
  gemm_k<1><<<dim3(8, 2), dim3(256), 0, stream>>>(Tt, W4b + (size_t)3072 * 1024,
                                                  b4 + 3072, RPRb, 256, 1024, 1024);

  transpose_v_k<<<dim3(4096), dim3(256), 0, stream>>>(QKVRb, Vt);
  bias_terms_k<<<dim3(272), dim3(256), 0, stream>>>(QKVRb, RPRb, ub, vb, ut, dtb);

  attn_k<<<dim3(2048), dim3(256), 0, stream>>>(QKVRb, RPKb, Vt, ut, dtb, vwb);

  // output projection: 4096 x 1024 x 1024, fp32 out
  gemm_k<0><<<dim3(8, 32), dim3(256), 0, stream>>>(vwb, Wob, bo, out, 4096, 1024, 1024);
}

// Round 6
// 254.317 us; speedup vs baseline: 1.8086x; 1.0781x over previous
//
#include <hip/hip_runtime.h>
#include <math.h>

constexpr int kB  = 16;
constexpr int kS  = 256;
constexpr int kD  = 1024;
constexpr int kH  = 16;
constexpr float kScale = 0.125f;  // 1/sqrt(64)

using bf16x8  = __attribute__((ext_vector_type(8))) short;
using floatx4 = __attribute__((ext_vector_type(4))) float;
typedef unsigned short u16;

__device__ __forceinline__ u16 f2bf(float x) {
  union { float f; unsigned u; } v; v.f = x;
  unsigned r = v.u + 0x7fffu + ((v.u >> 16) & 1u);
  return (u16)(r >> 16);
}
__device__ __forceinline__ float bf2f(u16 h) {
  union { unsigned u; float f; } v; v.u = ((unsigned)h) << 16;
  return v.f;
}

#define MFMA16(a, b, c) __builtin_amdgcn_mfma_f32_16x16x32_bf16((a), (b), (c), 0, 0, 0)
#define GLL16(gp, lp)                                                        \
  __builtin_amdgcn_global_load_lds(                                          \
      (const __attribute__((address_space(1))) unsigned int*)(gp),           \
      (__attribute__((address_space(3))) unsigned int*)(lp), 16, 0, 0)

// ---------------- sinusoid table rows: p in [0,256), pos = p-255, bf16 out --------
__global__ __launch_bounds__(256) void make_table_k(u16* __restrict__ T) {
  int idx = blockIdx.x * 256 + threadIdx.x;  // < 256*1024
  int p = idx >> 10;
  int i = idx & 1023;
  float ex = (float)(2 * (i / 2)) * (1.0f / 1024.0f);
  float scale = exp2f(ex * -13.287712379549449f);  // 10000^-ex
  float angle = (float)(p - 255) * scale;
  float v = (i & 1) ? cosf(angle) : sinf(angle);
  T[idx] = f2bf(v);
}

// ---------------- cast/pack (x4 vectorized); weight order [Wq;Wv;Wk;Wr] ----------
__global__ __launch_bounds__(256) void pack_k(
    const float* __restrict__ x, const float* __restrict__ Wq,
    const float* __restrict__ Wk, const float* __restrict__ Wv,
    const float* __restrict__ Wr, const float* __restrict__ Wo,
    const float* __restrict__ bq, const float* __restrict__ bk,
    const float* __restrict__ bv, const float* __restrict__ br,
    u16* __restrict__ xb, u16* __restrict__ W4b, u16* __restrict__ Wob,
    float* __restrict__ b4) {
  size_t i = ((size_t)blockIdx.x * 256 + threadIdx.x) * 4;
  const size_t NX = (size_t)4194304, NW = (size_t)1048576;
  const float* src;
  u16* dst;
  size_t o;
  if (i < NX) {
    src = x; dst = xb; o = i;
  } else if (i < NX + 4 * NW) {
    size_t j = i - NX;
    int sel = (int)(j >> 20);
    o = j & (NW - 1);
    src = sel == 0 ? Wq : sel == 1 ? Wv : sel == 2 ? Wk : Wr;
    dst = W4b + (size_t)sel * NW;
  } else if (i < NX + 5 * NW) {
    o = i - NX - 4 * NW;
    src = Wo; dst = Wob;
  } else if (i < NX + 5 * NW + 4096) {
    size_t j = i - NX - 5 * NW;
    int sel = (int)(j >> 10);
    o = j & 1023;
    src = sel == 0 ? bq : sel == 1 ? bv : sel == 2 ? bk : br;
    *reinterpret_cast<float4*>(b4 + j) = *reinterpret_cast<const float4*>(src + o);
    return;
  } else {
    return;
  }
  float4 v = *reinterpret_cast<const float4*>(src + o);
  ushort4 r;
  r.x = f2bf(v.x); r.y = f2bf(v.y); r.z = f2bf(v.z); r.w = f2bf(v.w);
  *reinterpret_cast<ushort4*>(dst + o) = r;
}

// ---------------- bf16 MFMA GEMM: C = A @ W^T + bias ----------------
// OUT_MODE 0: fp32 flat row-major. 1: bf16 flat row-major.
// 2: bf16 head-major multi-tensor: matsel=col>>10, h=(col>>6)&15, d=col&63,
//    b=row>>8, s=row&255 -> dst = matsel*(M<<10) + (((b*16+h)*256)+s)*64 + d.
template <int OUT_MODE>
__global__ __launch_bounds__(256) void gemm_k(
    const u16* __restrict__ A, const u16* __restrict__ W,
    const float* __restrict__ bias, void* __restrict__ Cv,
    int M, int N, int K) {
  __shared__ u16 Alds[128 * 64];
  __shared__ u16 Blds[128 * 64];
  const int bm = blockIdx.y * 128, bn = blockIdx.x * 128;
  const int t = threadIdx.x, w = t >> 6, l = t & 63;
  const int l15 = l & 15, quad = l >> 4;
  const int wm = w >> 1, wn = w & 1;
  const int lrow8 = l >> 3;
  const int kslot = l & 7;

  floatx4 acc[4][4] = {};

  for (int k0 = 0; k0 < K; k0 += 64) {
#pragma unroll
    for (int sg = 0; sg < 4; ++sg) {
      int mrow = sg * 32 + w * 8 + lrow8;
      int gk = (kslot ^ (mrow & 7)) << 3;
      const u16* gpa = A + (size_t)(bm + mrow) * K + k0 + gk;
      const u16* gpb = W + (size_t)(bn + mrow) * K + k0 + gk;
      u16* lpa = Alds + (sg * 32 + w * 8) * 64;
      u16* lpb = Blds + (sg * 32 + w * 8) * 64;
      GLL16(gpa, lpa);
      GLL16(gpb, lpb);
    }
    __syncthreads();
#pragma unroll
    for (int c = 0; c < 2; ++c) {
      bf16x8 af[4], bf[4];
#pragma unroll
      for (int mi = 0; mi < 4; ++mi) {
        int am = wm * 64 + mi * 16 + l15;
        af[mi] = *(const bf16x8*)(Alds + am * 64 + (((c * 4 + quad) ^ (am & 7)) << 3));
      }
#pragma unroll
      for (int ni = 0; ni < 4; ++ni) {
        int an = wn * 64 + ni * 16 + l15;
        bf[ni] = *(const bf16x8*)(Blds + an * 64 + (((c * 4 + quad) ^ (an & 7)) << 3));
      }
#pragma unroll
      for (int mi = 0; mi < 4; ++mi)
#pragma unroll
        for (int ni = 0; ni < 4; ++ni)
          acc[mi][ni] = MFMA16(af[mi], bf[ni], acc[mi][ni]);
    }
    __syncthreads();
  }

#pragma unroll
  for (int ni = 0; ni < 4; ++ni) {
    int col = bn + wn * 64 + ni * 16 + l15;
    float bv = bias[col];
#pragma unroll
    for (int mi = 0; mi < 4; ++mi) {
      int mrow = bm + wm * 64 + mi * 16 + quad * 4;
#pragma unroll
      for (int r = 0; r < 4; ++r) {
        float v = acc[mi][ni][r] + bv;
        int row = mrow + r;
        if (OUT_MODE == 0) {
          ((float*)Cv)[(size_t)row * N + col] = v;
        } else if (OUT_MODE == 1) {
          ((u16*)Cv)[(size_t)row * N + col] = f2bf(v);
        } else {
          int matsel = col >> 10;
          int hh = (col >> 6) & 15;
          int dd = col & 63;
          int bb = row >> 8;
          int ss = row & 255;
          size_t dst = (size_t)matsel * ((size_t)M << 10) +
                       ((size_t)(((bb << 4) + hh) << 8) + ss) * 64 + dd;
          ((u16*)Cv)[dst] = f2bf(v);
        }
      }
    }
  }
}

// ---------------- V transpose: Vt[b][h][d][z] <- Vh[b][h][z][d] ----------------
__global__ __launch_bounds__(256) void transpose_v_k(const u16* __restrict__ Vh,
                                                     u16* __restrict__ Vt) {
  __shared__ u16 tile[32][36];
  int blk = blockIdx.x;
  int dt1 = blk & 1;          // d-tile (0..1)
  int zt  = (blk >> 1) & 7;   // z-tile (0..7)
  int h   = (blk >> 4) & 15;
  int b   = blk >> 8;
  int t = threadIdx.x;
  int r = t >> 3, cc = t & 7;
  const u16* gp = Vh + ((size_t)(((b << 4) + h) << 8) + zt * 32 + r) * 64 + dt1 * 32 + cc * 4;
  ushort4 vv = *(const ushort4*)gp;
  tile[r][cc * 4 + 0] = vv.x;
  tile[r][cc * 4 + 1] = vv.y;
  tile[r][cc * 4 + 2] = vv.z;
  tile[r][cc * 4 + 3] = vv.w;
  __syncthreads();
  ushort4 o;
  o.x = tile[cc * 4 + 0][r];
  o.y = tile[cc * 4 + 1][r];
  o.z = tile[cc * 4 + 2][r];
  o.w = tile[cc * 4 + 3][r];
  u16* op = Vt + (size_t)((b << 4) + h) * 16384 + (size_t)(dt1 * 32 + r) * 256 + zt * 32 + cc * 4;
  *(ushort4*)op = o;
}

// ---------------- small bias-dot terms ----------------
// ut[(b*H+h)*256 + z] = u_bias[h] . Rh[b][h][z][:]
// dt[h*256 + p]       = v_bias[h] . RPRh[h][p][:]
__global__ __launch_bounds__(256) void bias_terms_k(
    const u16* __restrict__ Rh, const u16* __restrict__ RPRh,
    const float* __restrict__ ub, const float* __restrict__ vb,
    float* __restrict__ ut, float* __restrict__ dt) {
  int idx = blockIdx.x * 256 + threadIdx.x;
  const int NU = kB * kS * kH;  // 65536
  if (idx < NU) {
    int h = idx & 15, bz = idx >> 4;
    int b = bz >> 8, z = bz & 255;
    const bf16x8* kp = (const bf16x8*)(Rh + ((size_t)(((b << 4) + h) << 8) + z) * 64);
    const float* up = ub + h * 64;
    float a = 0.f;
#pragma unroll
    for (int i = 0; i < 8; ++i) {
      bf16x8 c = kp[i];
#pragma unroll
      for (int j = 0; j < 8; ++j) a += bf2f((u16)c[j]) * up[i * 8 + j];
    }
    ut[((b << 4) + h) * 256 + z] = a;
  } else if (idx < NU + kH * 256) {
    int j = idx - NU;
    int h = j >> 8, p = j & 255;
    const bf16x8* rp = (const bf16x8*)(RPRh + ((size_t)(h << 8) + p) * 64);
    const float* vp = vb + h * 64;
    float a = 0.f;
#pragma unroll
    for (int i = 0; i < 8; ++i) {
      bf16x8 c = rp[i];
#pragma unroll
      for (int jj = 0; jj < 8; ++jj) a += bf2f((u16)c[jj]) * vp[i * 8 + jj];
    }
    dt[j] = a;
  }
}

// ---------------- fused MFMA attention, head-major inputs, 32-row s-tiles --------
// Block = (b, h, 32-row s-tile); LDS ~35 KB. All fragment loads are contiguous
// 2KB wave loads (16 rows x 128B, head-major). Frag-array indices compile-time.
__global__ __launch_bounds__(256, 4) void attn_k(
    const u16* __restrict__ Qh, const u16* __restrict__ Kh,
    const u16* __restrict__ RPKh, const u16* __restrict__ Vt,
    const float* __restrict__ ut, const float* __restrict__ dt,
    u16* __restrict__ vw) {
  __shared__ float Sc[32][258];   // 33 KB
  __shared__ float Ut[256];
  __shared__ float Dt[256];
  __shared__ float Rinv[32];

  const int blk = blockIdx.x;
  const int st = 7 - (blk & 7);   // heavy tiles first
  const int h  = (blk >> 3) & 15;
  const int b  = blk >> 7;
  const int s0 = st * 32;
  const size_t bh256 = (size_t)(((b << 4) + h) << 8);  // row base for [b][h][*][64]

  const int t = threadIdx.x, w = t >> 6, l = t & 63;
  const int l15 = l & 15, quad = l >> 4;

  // stage ut/dt rows for this (b,h)
  Ut[t] = ut[((b << 4) + h) * 256 + t];
  Dt[t] = dt[(h << 8) + t];

  // Q A-fragments for both row-tiles (constant-indexed everywhere)
  bf16x8 qa[2][2];
#pragma unroll
  for (int rt = 0; rt < 2; ++rt) {
    const u16* qp = Qh + (bh256 + s0 + rt * 16 + l15) * 64 + quad * 8;
    qa[rt][0] = *(const bf16x8*)qp;
    qa[rt][1] = *(const bf16x8*)(qp + 32);
  }
  __syncthreads();

  // ---- QK^T + u_term: z-tiles split across waves ----
  const int zTiles = (s0 + 32) >> 4;  // 2*(st+1)
  for (int zt = w; zt < zTiles; zt += 4) {
    const int z0 = zt << 4;
    const u16* kp = Kh + (bh256 + z0 + l15) * 64 + quad * 8;
    bf16x8 kb0 = *(const bf16x8*)kp;
    bf16x8 kb1 = *(const bf16x8*)(kp + 32);
    float u = Ut[z0 + l15];
    const int rtmin = zt - (st << 1);  // wave-uniform
#pragma unroll
    for (int rt = 0; rt < 2; ++rt) {
      if (rt >= rtmin) {               // uniform branch, constant rt
        floatx4 acc = {};
        acc = MFMA16(qa[rt][0], kb0, acc);
        acc = MFMA16(qa[rt][1], kb1, acc);
#pragma unroll
        for (int r = 0; r < 4; ++r)
          Sc[rt * 16 + quad * 4 + r][z0 + l15] = acc[r] + u;
      }
    }
  }
  __syncthreads();

  // ---- QR: q_s . RPK[p] scatter-added into Sc[s][p+s-255]; rt compile-time ----
  {
    int cnt = 0;
#pragma unroll
    for (int rt = 0; rt < 2; ++rt) {
      const int rB = s0 + rt * 16;
      const int nj = (st << 1) + rt + 1;
      for (int j = 0; j < nj; ++j, ++cnt) {
        if ((cnt & 3) != w) continue;  // wave-uniform
        const int p0 = 240 - rB + (j << 4);
        const u16* rp = RPKh + ((size_t)(h << 8) + p0 + l15) * 64 + quad * 8;
        bf16x8 rb0 = *(const bf16x8*)rp;
        bf16x8 rb1 = *(const bf16x8*)(rp + 32);
        floatx4 acc = {};
        acc = MFMA16(qa[rt][0], rb0, acc);
        acc = MFMA16(qa[rt][1], rb1, acc);
        float dv = Dt[p0 + l15];
#pragma unroll
        for (int r = 0; r < 4; ++r) {
          int ro = quad * 4 + r;
          int z = p0 + l15 + rB + ro - 255;
          if (z >= 0) Sc[rt * 16 + ro][z] += acc[r] + dv;
        }
      }
    }
  }
  __syncthreads();

  // ---- causal softmax: 8 rows/wave, 8 lanes/row (unnormalized; 1/sum in LDS) ----
  {
    const int row = w * 8 + (l >> 3);  // 0..31
    const int c8 = l & 7;
    const int s = s0 + row;
    const int zfill = ((s0 + ((row >> 4) + 1) * 16 + 31) >> 5) << 5;  // strip PV range
    float m = -1e30f;
    for (int z = c8; z <= s; z += 8) m = fmaxf(m, Sc[row][z]);
    m = fmaxf(m, __shfl_xor(m, 1));
    m = fmaxf(m, __shfl_xor(m, 2));
    m = fmaxf(m, __shfl_xor(m, 4));
    m *= kScale;
    float sum = 0.f;
    for (int z = c8; z < zfill; z += 8) {
      float e = 0.f;
      if (z <= s) {
        e = __expf(Sc[row][z] * kScale - m);
        sum += e;
      }
      Sc[row][z] = e;
    }
    sum += __shfl_xor(sum, 1);
    sum += __shfl_xor(sum, 2);
    sum += __shfl_xor(sum, 4);
    if (c8 == 0) Rinv[row] = 1.f / sum;
  }
  __syncthreads();

  // ---- PV: wave = (strip, nt-pair); O[s,d] = sum_z P[s,z] * V[z,d] ----
  const int strip = w >> 1;          // 0..1
  const int ntb = (w & 1) * 2;       // 0 or 2
  const int sB = s0 + strip * 16;
  const int kcN = (sB + 16 + 31) >> 5;
  floatx4 oacc[2] = {};
  for (int kc = 0; kc < kcN; ++kc) {
    const float* prow = &Sc[strip * 16 + l15][kc * 32 + quad * 8];
    float p0 = prow[0], p1 = prow[1], p2 = prow[2], p3 = prow[3];
    float p4 = prow[4], p5 = prow[5], p6 = prow[6], p7 = prow[7];
    bf16x8 pa;
    pa[0] = (short)f2bf(p0); pa[1] = (short)f2bf(p1);
    pa[2] = (short)f2bf(p2); pa[3] = (short)f2bf(p3);
    pa[4] = (short)f2bf(p4); pa[5] = (short)f2bf(p5);
    pa[6] = (short)f2bf(p6); pa[7] = (short)f2bf(p7);
#pragma unroll
    for (int nt = 0; nt < 2; ++nt) {
      const u16* vp = Vt + (size_t)((b << 4) + h) * 16384 +
                      (size_t)((ntb + nt) * 16 + l15) * 256 + kc * 32 + quad * 8;
      bf16x8 vbf = *(const bf16x8*)vp;
      oacc[nt] = MFMA16(pa, vbf, oacc[nt]);
    }
  }

  // ---- epilogue: normalize, cast bf16, store (flat layout for out-proj GEMM) ----
#pragma unroll
  for (int r = 0; r < 4; ++r) {
    float ivr = Rinv[strip * 16 + quad * 4 + r];
    int srow = sB + quad * 4 + r;
#pragma unroll
    for (int nt = 0; nt < 2; ++nt) {
      float val = oacc[nt][r] * ivr;
      vw[(size_t)(b * 256 + srow) * 1024 + h * 64 + (ntb + nt) * 16 + l15] = f2bf(val);
    }
  }
}

extern "C" void kernel_launch(void* const* d_in, const int* in_sizes, int n_in,
                              void* d_out, int out_size, void* d_ws, size_t ws_size,
                              hipStream_t stream) {
  const float* x  = (const float*)d_in[0];
  const float* Wq = (const float*)d_in[1];
  const float* bq = (const float*)d_in[2];
  const float* Wk = (const float*)d_in[3];
  const float* bk = (const float*)d_in[4];
  const float* Wv = (const float*)d_in[5];
  const float* bv = (const float*)d_in[6];
  const float* Wr = (const float*)d_in[7];
  const float* br = (const float*)d_in[8];
  const float* ub = (const float*)d_in[9];
  const float* vb = (const float*)d_in[10];
  const float* Wo = (const float*)d_in[11];
  const float* bo = (const float*)d_in[12];
  float* out = (float*)d_out;

  char* base = (char*)d_ws;
  size_t off = 0;
  auto alloc = [&](size_t bytes) {
    void* p = base + off;
    off += (bytes + 255) & ~(size_t)255;
    return p;
  };

  const size_t MAT = (size_t)4194304;  // 4096*1024 elements per projection tensor
  u16*   Tt    = (u16*)alloc((size_t)256 * 1024 * 2);
  u16*   xb    = (u16*)alloc((size_t)4096 * 1024 * 2);
  u16*   W4b   = (u16*)alloc((size_t)4096 * 1024 * 2);   // [Wq;Wv;Wk;Wr]
  u16*   Wob   = (u16*)alloc((size_t)1024 * 1024 * 2);
  float* b4    = (float*)alloc((size_t)4096 * 4);        // [bq;bv;bk;br]
  u16*   QKVRh = (u16*)alloc(4 * MAT * 2);               // head-major Q,V,K,R
  u16*   RPh   = (u16*)alloc((size_t)2 * 262144 * 2);    // head-major RPK,RPR
  u16*   Vt    = (u16*)alloc((size_t)16 * 1024 * 256 * 2);
  float* ut    = (float*)alloc((size_t)65536 * 4);
  float* dtb   = (float*)alloc((size_t)16 * 256 * 4);
  u16*   vwb   = (u16*)alloc((size_t)4096 * 1024 * 2);

  u16* Qh = QKVRh;
  u16* Vh = QKVRh + MAT;
  u16* Kh = QKVRh + 2 * MAT;
  u16* Rh = QKVRh + 3 * MAT;
  u16* RPKh = RPh;
  u16* RPRh = RPh + 262144;

  make_table_k<<<dim3(1024), dim3(256), 0, stream>>>(Tt);
  pack_k<<<dim3(9220), dim3(256), 0, stream>>>(x, Wq, Wk, Wv, Wr, Wo, bq, bk, bv, br,
                                               xb, W4b, Wob, b4);

  // fused Q|V|K|KR projection: 4096 x 4096 x 1024, head-major epilogue
  gemm_k<2><<<dim3(32, 32), dim3(256), 0, stream>>>(xb, W4b, b4, QKVRh, 4096, 4096, 1024);
  // rel-pos projections (Wk,Wr adjacent): 256 x 2048 x 1024, head-major epilogue
  gemm_k<2><<<dim3(16, 2), dim3(256), 0, stream>>>(Tt, W4b + (size_t)2048 * 1024,
                                                   b4 + 2048, RPh, 256, 2048, 1024);

  transpose_v_k<<<dim3(4096), dim3(256), 0, stream>>>(Vh, Vt);
  bias_terms_k<<<dim3(272), dim3(256), 0, stream>>>(Rh, RPRh, ub, vb, ut, dtb);

  attn_k<<<dim3(2048), dim3(256), 0, stream>>>(Qh, Kh, RPKh, Vt, ut, dtb, vwb);

  // output projection: 4096 x 1024 x 1024, fp32 out
  gemm_k<0><<<dim3(8, 32), dim3(256), 0, stream>>>(vwb, Wob, bo, out, 4096, 1024, 1024);
}

// Round 7
// 238.214 us; speedup vs baseline: 1.9308x; 1.0676x over previous
//
#include <hip/hip_runtime.h>
#include <math.h>

constexpr int kB  = 16;
constexpr int kS  = 256;
constexpr int kD  = 1024;
constexpr int kH  = 16;
constexpr float kScale = 0.125f;  // 1/sqrt(64)

using bf16x8  = __attribute__((ext_vector_type(8))) short;
using floatx4 = __attribute__((ext_vector_type(4))) float;
typedef unsigned short u16;

__device__ __forceinline__ u16 f2bf(float x) {
  union { float f; unsigned u; } v; v.f = x;
  unsigned r = v.u + 0x7fffu + ((v.u >> 16) & 1u);
  return (u16)(r >> 16);
}
__device__ __forceinline__ float bf2f(u16 h) {
  union { unsigned u; float f; } v; v.u = ((unsigned)h) << 16;
  return v.f;
}

#define MFMA16(a, b, c) __builtin_amdgcn_mfma_f32_16x16x32_bf16((a), (b), (c), 0, 0, 0)
#define GLL16(gp, lp)                                                        \
  __builtin_amdgcn_global_load_lds(                                          \
      (const __attribute__((address_space(1))) unsigned int*)(gp),           \
      (__attribute__((address_space(3))) unsigned int*)(lp), 16, 0, 0)

// ---------------- pack + table: xA=[x;table], W4=[Wq;Wv;Wk;Wr], Wo, b4 ----------
__global__ __launch_bounds__(256) void pack_k(
    const float* __restrict__ x, const float* __restrict__ Wq,
    const float* __restrict__ Wk, const float* __restrict__ Wv,
    const float* __restrict__ Wr, const float* __restrict__ Wo,
    const float* __restrict__ bq, const float* __restrict__ bk,
    const float* __restrict__ bv, const float* __restrict__ br,
    u16* __restrict__ xA, u16* __restrict__ W4b, u16* __restrict__ Wob,
    float* __restrict__ b4) {
  size_t i = ((size_t)blockIdx.x * 256 + threadIdx.x) * 4;
  const size_t NX = (size_t)4194304, NW = (size_t)1048576;
  const size_t BEND = NX + 5 * NW + 4096;
  const float* src;
  u16* dst;
  size_t o;
  if (i < NX) {
    src = x; dst = xA; o = i;
  } else if (i < NX + 4 * NW) {
    size_t j = i - NX;
    int sel = (int)(j >> 20);
    o = j & (NW - 1);
    src = sel == 0 ? Wq : sel == 1 ? Wv : sel == 2 ? Wk : Wr;
    dst = W4b + (size_t)sel * NW;
  } else if (i < NX + 5 * NW) {
    o = i - NX - 4 * NW;
    src = Wo; dst = Wob;
  } else if (i < BEND) {
    size_t j = i - NX - 5 * NW;
    int sel = (int)(j >> 10);
    o = j & 1023;
    src = sel == 0 ? bq : sel == 1 ? bv : sel == 2 ? bk : br;
    *reinterpret_cast<float4*>(b4 + j) = *reinterpret_cast<const float4*>(src + o);
    return;
  } else if (i < BEND + 262144) {
    // sinusoid table rows p in [0,256), pos = p-255 -> xA rows 4096..4351
    size_t j = i - BEND;
    int p = (int)(j >> 10);
    int ibase = (int)(j & 1023);
    ushort4 r;
    u16* rr = (u16*)&r;
#pragma unroll
    for (int c = 0; c < 4; ++c) {
      int idx = ibase + c;
      float ex = (float)(2 * (idx / 2)) * (1.0f / 1024.0f);
      float scale = exp2f(ex * -13.287712379549449f);  // 10000^-ex
      float angle = (float)(p - 255) * scale;
      rr[c] = f2bf((idx & 1) ? cosf(angle) : sinf(angle));
    }
    *reinterpret_cast<ushort4*>(xA + NX + j) = r;
    return;
  } else {
    return;
  }
  float4 v = *reinterpret_cast<const float4*>(src + o);
  ushort4 r;
  r.x = f2bf(v.x); r.y = f2bf(v.y); r.z = f2bf(v.z); r.w = f2bf(v.w);
  *reinterpret_cast<ushort4*>(dst + o) = r;
}

// ---------------- bf16 MFMA GEMM: C = A @ W^T + bias ----------------
// OUT_MODE 0: fp32 flat row-major.
// OUT_MODE 2: bf16 head-major multi-tensor; rows >= 4096 are table rows:
//   matsel=col>>10 (Q,V,K,R), h=(col>>6)&15, d=col&63.
//   row<4096:  dst = matsel*4194304 + (((b*16+h)*256)+s)*64 + d
//   row>=4096: matsel 2,3 -> RPKh/RPRh at 4*4194304 + (matsel-2)*262144
//              + ((h*256)+p)*64 + d ; matsel 0,1 discarded.
template <int OUT_MODE>
__global__ __launch_bounds__(256) void gemm_k(
    const u16* __restrict__ A, const u16* __restrict__ W,
    const float* __restrict__ bias, void* __restrict__ Cv,
    int M, int N, int K) {
  __shared__ u16 Alds[128 * 64];
  __shared__ u16 Blds[128 * 64];
  const int bm = blockIdx.y * 128, bn = blockIdx.x * 128;
  const int t = threadIdx.x, w = t >> 6, l = t & 63;
  const int l15 = l & 15, quad = l >> 4;
  const int wm = w >> 1, wn = w & 1;
  const int lrow8 = l >> 3;
  const int kslot = l & 7;

  floatx4 acc[4][4] = {};

  for (int k0 = 0; k0 < K; k0 += 64) {
#pragma unroll
    for (int sg = 0; sg < 4; ++sg) {
      int mrow = sg * 32 + w * 8 + lrow8;
      int gk = (kslot ^ (mrow & 7)) << 3;
      const u16* gpa = A + (size_t)(bm + mrow) * K + k0 + gk;
      const u16* gpb = W + (size_t)(bn + mrow) * K + k0 + gk;
      u16* lpa = Alds + (sg * 32 + w * 8) * 64;
      u16* lpb = Blds + (sg * 32 + w * 8) * 64;
      GLL16(gpa, lpa);
      GLL16(gpb, lpb);
    }
    __syncthreads();
#pragma unroll
    for (int c = 0; c < 2; ++c) {
      bf16x8 af[4], bf[4];
#pragma unroll
      for (int mi = 0; mi < 4; ++mi) {
        int am = wm * 64 + mi * 16 + l15;
        af[mi] = *(const bf16x8*)(Alds + am * 64 + (((c * 4 + quad) ^ (am & 7)) << 3));
      }
#pragma unroll
      for (int ni = 0; ni < 4; ++ni) {
        int an = wn * 64 + ni * 16 + l15;
        bf[ni] = *(const bf16x8*)(Blds + an * 64 + (((c * 4 + quad) ^ (an & 7)) << 3));
      }
#pragma unroll
      for (int mi = 0; mi < 4; ++mi)
#pragma unroll
        for (int ni = 0; ni < 4; ++ni)
          acc[mi][ni] = MFMA16(af[mi], bf[ni], acc[mi][ni]);
    }
    __syncthreads();
  }

#pragma unroll
  for (int ni = 0; ni < 4; ++ni) {
    int col = bn + wn * 64 + ni * 16 + l15;
    float bv = bias[col];
#pragma unroll
    for (int mi = 0; mi < 4; ++mi) {
      int mrow = bm + wm * 64 + mi * 16 + quad * 4;
#pragma unroll
      for (int r = 0; r < 4; ++r) {
        float v = acc[mi][ni][r] + bv;
        int row = mrow + r;
        if (OUT_MODE == 0) {
          ((float*)Cv)[(size_t)row * N + col] = v;
        } else {
          int matsel = col >> 10;
          int hh = (col >> 6) & 15;
          int dd = col & 63;
          if (row < 4096) {
            int bb = row >> 8, ss = row & 255;
            size_t dst = (size_t)matsel * 4194304 +
                         ((size_t)(((bb << 4) + hh) << 8) + ss) * 64 + dd;
            ((u16*)Cv)[dst] = f2bf(v);
          } else if (matsel >= 2) {
            int pp = row - 4096;
            size_t dst = (size_t)4 * 4194304 + (size_t)(matsel - 2) * 262144 +
                         ((size_t)((hh << 8) + pp)) * 64 + dd;
            ((u16*)Cv)[dst] = f2bf(v);
          }
        }
      }
    }
  }
}

// ---------------- fused attention: one block per (b,h), K/V in LDS ----------------
// 512 threads (8 waves, 2/SIMD). K staged via global_load_lds (XOR-swizzled);
// V transposed into LDS at staging; ut/dt computed in-block. 8 s-tiles of 32
// rows looped inside. QK writes Sc[s][z], QR writes Sc2[s][p] (no overlap ->
// one merged phase); softmax combines via p = z-s+255. All frag-array indices
// compile-time (round-3 lesson).
__global__ __launch_bounds__(512, 2) void attn_k(
    const u16* __restrict__ Qh, const u16* __restrict__ Kh,
    const u16* __restrict__ Vh, const u16* __restrict__ RPKh,
    const u16* __restrict__ Rh, const u16* __restrict__ RPRh,
    const float* __restrict__ ub, const float* __restrict__ vb,
    u16* __restrict__ vw) {
  __shared__ u16 Klds[256 * 64];     // 32 KB, XOR-swizzled rows
  __shared__ u16 Vt[64][280];        // 35 KB, V transposed (pad: 2-way banks only)
  __shared__ float Sc[32][257];      // 32.9 KB  scores by z
  __shared__ float Sc2[32][257];     // 32.9 KB  rel scores by p
  __shared__ float Ut[256], Dt[256], Rinv[32];

  const int bh = blockIdx.x;         // b*16 + h
  const int h = bh & 15;
  const int b = bh >> 4;
  const size_t bh256 = (size_t)bh << 8;

  const int t = threadIdx.x, w = t >> 6, l = t & 63;
  const int l15 = l & 15, quad = l >> 4;

  // ---- staging: K (GLL16), V^T (LDS transpose), Ut, Dt ----
  {
    const int lrow8 = l >> 3, kslot = l & 7;
#pragma unroll
    for (int i = 0; i < 4; ++i) {
      int row = w * 32 + i * 8 + lrow8;
      int gk = (kslot ^ (row & 7)) << 3;
      const u16* gp = Kh + (bh256 + row) * 64 + gk;
      u16* lp = Klds + (w * 32 + i * 8) * 64;
      GLL16(gp, lp);
    }
  }
  {
    int z = t & 255, dh = t >> 8;    // dh: 0..1 (wave-uniform)
    const u16* gp = Vh + (bh256 + z) * 64 + dh * 32;
    ushort4 vv[8];
#pragma unroll
    for (int i = 0; i < 8; ++i) vv[i] = *(const ushort4*)(gp + i * 4);
#pragma unroll
    for (int i = 0; i < 8; ++i) {
      Vt[dh * 32 + i * 4 + 0][z] = vv[i].x;
      Vt[dh * 32 + i * 4 + 1][z] = vv[i].y;
      Vt[dh * 32 + i * 4 + 2][z] = vv[i].z;
      Vt[dh * 32 + i * 4 + 3][z] = vv[i].w;
    }
  }
  if (t < 256) {
    const u16* rp = Rh + (bh256 + t) * 64;
    const float* up = ub + h * 64;
    float a = 0.f;
#pragma unroll
    for (int i = 0; i < 8; ++i) {
      bf16x8 c = *(const bf16x8*)(rp + i * 8);
#pragma unroll
      for (int j = 0; j < 8; ++j) a += bf2f((u16)c[j]) * up[i * 8 + j];
    }
    Ut[t] = a;
  } else {
    int p = t - 256;
    const u16* rp = RPRh + ((size_t)(h << 8) + p) * 64;
    const float* vp = vb + h * 64;
    float a = 0.f;
#pragma unroll
    for (int i = 0; i < 8; ++i) {
      bf16x8 c = *(const bf16x8*)(rp + i * 8);
#pragma unroll
      for (int j = 0; j < 8; ++j) a += bf2f((u16)c[j]) * vp[i * 8 + j];
    }
    Dt[p] = a;
  }
  __syncthreads();

  // ---- loop over 8 s-tiles of 32 rows ----
  for (int st = 0; st < 8; ++st) {
    const int s0 = st * 32;

    // Q A-fragments for both row-tiles (global, L1-shared across waves)
    bf16x8 qa[2][2];
#pragma unroll
    for (int rt = 0; rt < 2; ++rt) {
      const u16* qp = Qh + (bh256 + s0 + rt * 16 + l15) * 64 + quad * 8;
      qa[rt][0] = *(const bf16x8*)qp;
      qa[rt][1] = *(const bf16x8*)(qp + 32);
    }

    // merged QK (-> Sc) + QR (-> Sc2) phase; tasks round-robin over 8 waves
    {
      int cnt = 0;
#pragma unroll
      for (int rt = 0; rt < 2; ++rt) {
        const int rB = s0 + rt * 16;
        const int nzt = 2 * st + rt + 1;
        for (int zt = 0; zt < nzt; ++zt, ++cnt) {
          if ((cnt & 7) != w) continue;  // wave-uniform
          const int zr = (zt << 4) + l15;
          const u16* krow = Klds + zr * 64;
          bf16x8 kb0 = *(const bf16x8*)(krow + ((quad ^ (zr & 7)) << 3));
          bf16x8 kb1 = *(const bf16x8*)(krow + (((quad + 4) ^ (zr & 7)) << 3));
          floatx4 acc = {};
          acc = MFMA16(qa[rt][0], kb0, acc);
          acc = MFMA16(qa[rt][1], kb1, acc);
          float u = Ut[zr];
#pragma unroll
          for (int r = 0; r < 4; ++r)
            Sc[rt * 16 + quad * 4 + r][zr] = acc[r] + u;
        }
        const int nj = nzt;
        for (int j = 0; j < nj; ++j, ++cnt) {
          if ((cnt & 7) != w) continue;
          const int pr = 240 - rB + (j << 4) + l15;
          const u16* rp = RPKh + ((size_t)(h << 8) + pr) * 64 + quad * 8;
          bf16x8 rb0 = *(const bf16x8*)rp;
          bf16x8 rb1 = *(const bf16x8*)(rp + 32);
          floatx4 acc = {};
          acc = MFMA16(qa[rt][0], rb0, acc);
          acc = MFMA16(qa[rt][1], rb1, acc);
          float dv = Dt[pr];
#pragma unroll
          for (int r = 0; r < 4; ++r)
            Sc2[rt * 16 + quad * 4 + r][pr] = acc[r] + dv;
        }
      }
    }
    __syncthreads();

    // softmax: 4 rows/wave, 16 lanes/row; P -> Sc (zero-filled to 32*(st+1))
    {
      const int row = w * 4 + (l >> 4);
      const int c16 = l & 15;
      const int s = s0 + row;
      const int zfill = 32 * (st + 1);
      float m = -1e30f;
      for (int z = c16; z <= s; z += 16)
        m = fmaxf(m, Sc[row][z] + Sc2[row][z - s + 255]);
      m = fmaxf(m, __shfl_xor(m, 1));
      m = fmaxf(m, __shfl_xor(m, 2));
      m = fmaxf(m, __shfl_xor(m, 4));
      m = fmaxf(m, __shfl_xor(m, 8));
      m *= kScale;
      float sum = 0.f;
      for (int z = c16; z < zfill; z += 16) {
        float e = 0.f;
        if (z <= s) {
          e = __expf((Sc[row][z] + Sc2[row][z - s + 255]) * kScale - m);
          sum += e;
        }
        Sc[row][z] = e;
      }
      sum += __shfl_xor(sum, 1);
      sum += __shfl_xor(sum, 2);
      sum += __shfl_xor(sum, 4);
      sum += __shfl_xor(sum, 8);
      if (c16 == 0) Rinv[row] = 1.f / sum;
    }
    __syncthreads();

    // PV: wave = (strip = w>>2, nt = w&3); V from LDS
    {
      const int strip = w >> 2, nt = w & 3;
      const int sB = s0 + strip * 16;
      floatx4 oacc = {};
      for (int kc = 0; kc <= st; ++kc) {
        const float* prow = &Sc[strip * 16 + l15][kc * 32 + quad * 8];
        bf16x8 pa;
        pa[0] = (short)f2bf(prow[0]); pa[1] = (short)f2bf(prow[1]);
        pa[2] = (short)f2bf(prow[2]); pa[3] = (short)f2bf(prow[3]);
        pa[4] = (short)f2bf(prow[4]); pa[5] = (short)f2bf(prow[5]);
        pa[6] = (short)f2bf(prow[6]); pa[7] = (short)f2bf(prow[7]);
        const u16* vp = &Vt[nt * 16 + l15][kc * 32 + quad * 8];
        bf16x8 vbf = *(const bf16x8*)vp;
        oacc = MFMA16(pa, vbf, oacc);
      }
#pragma unroll
      for (int r = 0; r < 4; ++r) {
        float ivr = Rinv[strip * 16 + quad * 4 + r];
        int srow = sB + quad * 4 + r;
        vw[(size_t)(b * 256 + srow) * 1024 + h * 64 + nt * 16 + l15] =
            f2bf(oacc[r] * ivr);
      }
    }
    __syncthreads();  // protect Sc before next tile's QK writes
  }
}

extern "C" void kernel_launch(void* const* d_in, const int* in_sizes, int n_in,
                              void* d_out, int out_size, void* d_ws, size_t ws_size,
                              hipStream_t stream) {
  const float* x  = (const float*)d_in[0];
  const float* Wq = (const float*)d_in[1];
  const float* bq = (const float*)d_in[2];
  const float* Wk = (const float*)d_in[3];
  const float* bk = (const float*)d_in[4];
  const float* Wv = (const float*)d_in[5];
  const float* bv = (const float*)d_in[6];
  const float* Wr = (const float*)d_in[7];
  const float* br = (const float*)d_in[8];
  const float* ub = (const float*)d_in[9];
  const float* vb = (const float*)d_in[10];
  const float* Wo = (const float*)d_in[11];
  const float* bo = (const float*)d_in[12];
  float* out = (float*)d_out;

  char* base = (char*)d_ws;
  size_t off = 0;
  auto alloc = [&](size_t bytes) {
    void* p = base + off;
    off += (bytes + 255) & ~(size_t)255;
    return p;
  };

  const size_t MAT = (size_t)4194304;  // 4096*1024
  u16*   xA    = (u16*)alloc((size_t)4352 * 1024 * 2);       // [x ; table]
  u16*   W4b   = (u16*)alloc((size_t)4096 * 1024 * 2);       // [Wq;Wv;Wk;Wr]
  u16*   Wob   = (u16*)alloc((size_t)1024 * 1024 * 2);
  float* b4    = (float*)alloc((size_t)4096 * 4);            // [bq;bv;bk;br]
  u16*   Ph    = (u16*)alloc((4 * MAT + 2 * 262144) * 2);    // Qh,Vh,Kh,Rh,RPKh,RPRh
  u16*   vwb   = (u16*)alloc((size_t)4096 * 1024 * 2);

  u16* Qh   = Ph;
  u16* Vh   = Ph + MAT;
  u16* Kh   = Ph + 2 * MAT;
  u16* Rh   = Ph + 3 * MAT;
  u16* RPKh = Ph + 4 * MAT;
  u16* RPRh = Ph + 4 * MAT + 262144;

  // pack + table: (4194304 + 5242880 + 4096 + 262144)/1024 = 9476 blocks
  pack_k<<<dim3(9476), dim3(256), 0, stream>>>(x, Wq, Wk, Wv, Wr, Wo, bq, bk, bv, br,
                                               xA, W4b, Wob, b4);

  // fused Q|V|K|R + relpos projections: 4352 x 4096 x 1024, head-major epilogue
  gemm_k<2><<<dim3(32, 34), dim3(256), 0, stream>>>(xA, W4b, b4, Ph, 4352, 4096, 1024);

  // fused attention: one block per (b,h)
  attn_k<<<dim3(256), dim3(512), 0, stream>>>(Qh, Kh, Vh, RPKh, Rh, RPRh, ub, vb, vwb);

  // output projection: 4096 x 1024 x 1024, fp32 out
  gemm_k<0><<<dim3(8, 32), dim3(256), 0, stream>>>(vwb, Wob, bo, out, 4096, 1024, 1024);
}

// Round 8
// 234.753 us; speedup vs baseline: 1.9593x; 1.0147x over previous
//
#include <hip/hip_runtime.h>
#include <math.h>

constexpr int kB  = 16;
constexpr int kS  = 256;
constexpr int kD  = 1024;
constexpr int kH  = 16;
constexpr float kScale = 0.125f;  // 1/sqrt(64)

using bf16x8  = __attribute__((ext_vector_type(8))) short;
using floatx4 = __attribute__((ext_vector_type(4))) float;
typedef unsigned short u16;

__device__ __forceinline__ u16 f2bf(float x) {
  union { float f; unsigned u; } v; v.f = x;
  unsigned r = v.u + 0x7fffu + ((v.u >> 16) & 1u);
  return (u16)(r >> 16);
}
__device__ __forceinline__ float bf2f(u16 h) {
  union { unsigned u; float f; } v; v.u = ((unsigned)h) << 16;
  return v.f;
}

#define MFMA16(a, b, c) __builtin_amdgcn_mfma_f32_16x16x32_bf16((a), (b), (c), 0, 0, 0)
#define GLL16(gp, lp)                                                        \
  __builtin_amdgcn_global_load_lds(                                          \
      (const __attribute__((address_space(1))) unsigned int*)(gp),           \
      (__attribute__((address_space(3))) unsigned int*)(lp), 16, 0, 0)

// ---------------- pack + table: xA=[x;table], W3=[Wq;Wv;Wk], Wo, b3 ----------
__global__ __launch_bounds__(256) void pack_k(
    const float* __restrict__ x, const float* __restrict__ Wq,
    const float* __restrict__ Wk, const float* __restrict__ Wv,
    const float* __restrict__ Wo,
    const float* __restrict__ bq, const float* __restrict__ bk,
    const float* __restrict__ bv,
    u16* __restrict__ xA, u16* __restrict__ W3b, u16* __restrict__ Wob,
    float* __restrict__ b3) {
  size_t i = ((size_t)blockIdx.x * 256 + threadIdx.x) * 4;
  const size_t NX = (size_t)4194304, NW = (size_t)1048576;
  const size_t BEND = NX + 4 * NW + 3072;
  const float* src;
  u16* dst;
  size_t o;
  if (i < NX) {
    src = x; dst = xA; o = i;
  } else if (i < NX + 3 * NW) {
    size_t j = i - NX;
    int sel = (int)(j >> 20);
    o = j & (NW - 1);
    src = sel == 0 ? Wq : sel == 1 ? Wv : Wk;
    dst = W3b + (size_t)sel * NW;
  } else if (i < NX + 4 * NW) {
    o = i - NX - 3 * NW;
    src = Wo; dst = Wob;
  } else if (i < BEND) {
    size_t j = i - NX - 4 * NW;
    int sel = (int)(j >> 10);
    o = j & 1023;
    src = sel == 0 ? bq : sel == 1 ? bv : bk;
    *reinterpret_cast<float4*>(b3 + j) = *reinterpret_cast<const float4*>(src + o);
    return;
  } else if (i < BEND + 262144) {
    // sinusoid table rows p in [0,256), pos = p-255 -> xA rows 4096..4351
    size_t j = i - BEND;
    int p = (int)(j >> 10);
    int ibase = (int)(j & 1023);
    ushort4 r;
    u16* rr = (u16*)&r;
#pragma unroll
    for (int c = 0; c < 4; ++c) {
      int idx = ibase + c;
      float ex = (float)(2 * (idx / 2)) * (1.0f / 1024.0f);
      float scale = exp2f(ex * -13.287712379549449f);  // 10000^-ex
      float angle = (float)(p - 255) * scale;
      rr[c] = f2bf((idx & 1) ? cosf(angle) : sinf(angle));
    }
    *reinterpret_cast<ushort4*>(xA + NX + j) = r;
    return;
  } else {
    return;
  }
  float4 v = *reinterpret_cast<const float4*>(src + o);
  ushort4 r;
  r.x = f2bf(v.x); r.y = f2bf(v.y); r.z = f2bf(v.z); r.w = f2bf(v.w);
  *reinterpret_cast<ushort4*>(dst + o) = r;
}

// ---------------- rank-16 fold of Wr with u/v: W3b rows 3072..3103, b3 tail ------
// W3b[3072+j][c] = sum_d bvec_j[d] * Wr[(j&15)*64+d][c],  bvec = u (j<16) / v.
// b3[3072+j] = bvec_j . br_seg ; b3[3104..3199] = 0.
__global__ __launch_bounds__(256) void uv_fold_k(
    const float* __restrict__ Wr, const float* __restrict__ br,
    const float* __restrict__ ub, const float* __restrict__ vb,
    u16* __restrict__ W3b, float* __restrict__ b3) {
  int gid = blockIdx.x * 256 + threadIdx.x;  // 32768
  int j = gid >> 10, c = gid & 1023;
  int h = j & 15;
  const float* bvec = (j < 16 ? ub : vb) + h * 64;
  const float* wcol = Wr + (size_t)(h * 64) * 1024 + c;
  float a = 0.f;
#pragma unroll
  for (int d = 0; d < 64; ++d) a += bvec[d] * wcol[(size_t)d * 1024];
  W3b[(size_t)(3072 + j) * 1024 + c] = f2bf(a);
  if (gid < 128) {
    float s = 0.f;
    if (gid < 32) {
      const float* bv2 = (gid < 16 ? ub : vb) + (gid & 15) * 64;
      const float* brp = br + (gid & 15) * 64;
      for (int d = 0; d < 64; ++d) s += bv2[d] * brp[d];
    }
    b3[3072 + gid] = s;
  }
}

// ---------------- bf16 MFMA GEMM: C = A @ W^T + bias ----------------
// BM = 128 (256 thr, 2x2 waves) or 64 (128 thr, 1x2 waves). BN = 128 fixed.
// OUT_MODE 0: fp32 flat row-major.
// OUT_MODE 2: head-major multi-tensor epilogue (see routing below); rows >=
//   4096 are table rows; cols 3072..3087 -> utb fp32, 3088..3103 -> dtb fp32.
template <int OUT_MODE, int BM>
__global__ __launch_bounds__(BM * 2) void gemm_k(
    const u16* __restrict__ A, const u16* __restrict__ W,
    const float* __restrict__ bias, void* __restrict__ Cv,
    int M, int N, int K, float* __restrict__ utb, float* __restrict__ dtb) {
  __shared__ u16 Alds[BM * 64];
  __shared__ u16 Blds[128 * 64];
  const int NWAVE = BM / 64;  // waves = 2*NWAVE... (BM=128:4, BM=64:2)
  const int bm = blockIdx.y * BM, bn = blockIdx.x * 128;
  const int t = threadIdx.x, w = t >> 6, l = t & 63;
  const int l15 = l & 15, quad = l >> 4;
  const int wm = (BM == 128) ? (w >> 1) : 0;
  const int wn = (BM == 128) ? (w & 1) : w;
  const int lrow8 = l >> 3;
  const int kslot = l & 7;
  const int WROWS = (BM == 128) ? 32 : 16;  // rows staged per sg step (all waves)

  floatx4 acc[4][4] = {};

  for (int k0 = 0; k0 < K; k0 += 64) {
#pragma unroll
    for (int sg = 0; sg < BM / WROWS; ++sg) {
      int mrow = sg * WROWS + w * 8 + lrow8;
      int gk = (kslot ^ (mrow & 7)) << 3;
      GLL16(A + (size_t)(bm + mrow) * K + k0 + gk, Alds + (sg * WROWS + w * 8) * 64);
    }
#pragma unroll
    for (int sg = 0; sg < 128 / WROWS; ++sg) {
      int nrow = sg * WROWS + w * 8 + lrow8;
      int gk = (kslot ^ (nrow & 7)) << 3;
      GLL16(W + (size_t)(bn + nrow) * K + k0 + gk, Blds + (sg * WROWS + w * 8) * 64);
    }
    __syncthreads();
#pragma unroll
    for (int c = 0; c < 2; ++c) {
      bf16x8 af[4], bf[4];
#pragma unroll
      for (int mi = 0; mi < 4; ++mi) {
        int am = wm * 64 + mi * 16 + l15;
        af[mi] = *(const bf16x8*)(Alds + am * 64 + (((c * 4 + quad) ^ (am & 7)) << 3));
      }
#pragma unroll
      for (int ni = 0; ni < 4; ++ni) {
        int an = wn * 64 + ni * 16 + l15;
        bf[ni] = *(const bf16x8*)(Blds + an * 64 + (((c * 4 + quad) ^ (an & 7)) << 3));
      }
#pragma unroll
      for (int mi = 0; mi < 4; ++mi)
#pragma unroll
        for (int ni = 0; ni < 4; ++ni)
          acc[mi][ni] = MFMA16(af[mi], bf[ni], acc[mi][ni]);
    }
    __syncthreads();
  }

#pragma unroll
  for (int ni = 0; ni < 4; ++ni) {
    int col = bn + wn * 64 + ni * 16 + l15;
    float bv = bias[col];
#pragma unroll
    for (int mi = 0; mi < 4; ++mi) {
      int mrow = bm + wm * 64 + mi * 16 + quad * 4;
#pragma unroll
      for (int r = 0; r < 4; ++r) {
        float v = acc[mi][ni][r] + bv;
        int row = mrow + r;
        if (OUT_MODE == 0) {
          ((float*)Cv)[(size_t)row * N + col] = v;
        } else {
          if (col < 3072) {
            int matsel = col >> 10;        // 0=Q,1=V,2=K
            int hh = (col >> 6) & 15, dd = col & 63;
            if (row < 4096) {
              int bb = row >> 8, ss = row & 255;
              ((u16*)Cv)[(size_t)matsel * 4194304 +
                         ((size_t)(((bb << 4) + hh) << 8) + ss) * 64 + dd] = f2bf(v);
            } else if (matsel == 2) {      // table @ Wk^T -> RPKh
              int pp = row - 4096;
              ((u16*)Cv)[(size_t)3 * 4194304 +
                         ((size_t)((hh << 8) + pp)) * 64 + dd] = f2bf(v);
            }
          } else if (col < 3088) {
            if (row < 4096)
              utb[((row >> 8) * 16 + (col - 3072)) * 256 + (row & 255)] = v;
          } else if (col < 3104) {
            if (row >= 4096)
              dtb[(col - 3088) * 256 + (row - 4096)] = v;
          }
        }
      }
    }
  }
}

// ---------------- fused attention: one block per (b,h), K/V in LDS ----------------
// 512 threads (8 waves). K staged via global_load_lds (XOR-swizzled); V
// transposed into LDS at staging; ut/dt preloaded (computed by GEMM fold).
// QK writes Sc[s][z], QR writes Sc2[s][p]; softmax combines via p = z-s+255.
// All frag-array indices compile-time (round-3 lesson).
__global__ __launch_bounds__(512, 2) void attn_k(
    const u16* __restrict__ Qh, const u16* __restrict__ Kh,
    const u16* __restrict__ Vh, const u16* __restrict__ RPKh,
    const float* __restrict__ ut, const float* __restrict__ dt,
    u16* __restrict__ vw) {
  __shared__ u16 Klds[256 * 64];     // 32 KB, XOR-swizzled rows
  __shared__ u16 Vt[64][280];        // 35 KB, V transposed
  __shared__ float Sc[32][257];      // scores by z
  __shared__ float Sc2[32][257];     // rel scores by p
  __shared__ float Ut[256], Dt[256], Rinv[32];

  const int bh = blockIdx.x;         // b*16 + h
  const int h = bh & 15;
  const int b = bh >> 4;
  const size_t bh256 = (size_t)bh << 8;

  const int t = threadIdx.x, w = t >> 6, l = t & 63;
  const int l15 = l & 15, quad = l >> 4;

  // ---- staging: K (GLL16), V^T (LDS transpose), Ut, Dt ----
  {
    const int lrow8 = l >> 3, kslot = l & 7;
#pragma unroll
    for (int i = 0; i < 4; ++i) {
      int row = w * 32 + i * 8 + lrow8;
      int gk = (kslot ^ (row & 7)) << 3;
      GLL16(Kh + (bh256 + row) * 64 + gk, Klds + (w * 32 + i * 8) * 64);
    }
  }
  {
    int z = t & 255, dh = t >> 8;    // dh: 0..1 (wave-uniform)
    const u16* gp = Vh + (bh256 + z) * 64 + dh * 32;
    ushort4 vv[8];
#pragma unroll
    for (int i = 0; i < 8; ++i) vv[i] = *(const ushort4*)(gp + i * 4);
#pragma unroll
    for (int i = 0; i < 8; ++i) {
      Vt[dh * 32 + i * 4 + 0][z] = vv[i].x;
      Vt[dh * 32 + i * 4 + 1][z] = vv[i].y;
      Vt[dh * 32 + i * 4 + 2][z] = vv[i].z;
      Vt[dh * 32 + i * 4 + 3][z] = vv[i].w;
    }
  }
  if (t < 256) Ut[t] = ut[bh256 + t];
  else         Dt[t - 256] = dt[((size_t)h << 8) + (t - 256)];
  __syncthreads();

  // ---- loop over 8 s-tiles of 32 rows ----
  for (int st = 0; st < 8; ++st) {
    const int s0 = st * 32;

    bf16x8 qa[2][2];
#pragma unroll
    for (int rt = 0; rt < 2; ++rt) {
      const u16* qp = Qh + (bh256 + s0 + rt * 16 + l15) * 64 + quad * 8;
      qa[rt][0] = *(const bf16x8*)qp;
      qa[rt][1] = *(const bf16x8*)(qp + 32);
    }

    // merged QK (-> Sc) + QR (-> Sc2); tasks round-robin over 8 waves
    {
      int cnt = 0;
#pragma unroll
      for (int rt = 0; rt < 2; ++rt) {
        const int rB = s0 + rt * 16;
        const int nzt = 2 * st + rt + 1;
        for (int zt = 0; zt < nzt; ++zt, ++cnt) {
          if ((cnt & 7) != w) continue;  // wave-uniform
          const int zr = (zt << 4) + l15;
          const u16* krow = Klds + zr * 64;
          bf16x8 kb0 = *(const bf16x8*)(krow + ((quad ^ (zr & 7)) << 3));
          bf16x8 kb1 = *(const bf16x8*)(krow + (((quad + 4) ^ (zr & 7)) << 3));
          floatx4 acc = {};
          acc = MFMA16(qa[rt][0], kb0, acc);
          acc = MFMA16(qa[rt][1], kb1, acc);
          float u = Ut[zr];
#pragma unroll
          for (int r = 0; r < 4; ++r)
            Sc[rt * 16 + quad * 4 + r][zr] = acc[r] + u;
        }
        for (int j = 0; j < nzt; ++j, ++cnt) {
          if ((cnt & 7) != w) continue;
          const int pr = 240 - rB + (j << 4) + l15;
          const u16* rp = RPKh + ((size_t)(h << 8) + pr) * 64 + quad * 8;
          bf16x8 rb0 = *(const bf16x8*)rp;
          bf16x8 rb1 = *(const bf16x8*)(rp + 32);
          floatx4 acc = {};
          acc = MFMA16(qa[rt][0], rb0, acc);
          acc = MFMA16(qa[rt][1], rb1, acc);
          float dv = Dt[pr];
#pragma unroll
          for (int r = 0; r < 4; ++r)
            Sc2[rt * 16 + quad * 4 + r][pr] = acc[r] + dv;
        }
      }
    }
    __syncthreads();

    // softmax: 4 rows/wave, 16 lanes/row; P -> Sc
    {
      const int row = w * 4 + (l >> 4);
      const int c16 = l & 15;
      const int s = s0 + row;
      const int zfill = 32 * (st + 1);
      float m = -1e30f;
      for (int z = c16; z <= s; z += 16)
        m = fmaxf(m, Sc[row][z] + Sc2[row][z - s + 255]);
      m = fmaxf(m, __shfl_xor(m, 1));
      m = fmaxf(m, __shfl_xor(m, 2));
      m = fmaxf(m, __shfl_xor(m, 4));
      m = fmaxf(m, __shfl_xor(m, 8));
      m *= kScale;
      float sum = 0.f;
      for (int z = c16; z < zfill; z += 16) {
        float e = 0.f;
        if (z <= s) {
          e = __expf((Sc[row][z] + Sc2[row][z - s + 255]) * kScale - m);
          sum += e;
        }
        Sc[row][z] = e;
      }
      sum += __shfl_xor(sum, 1);
      sum += __shfl_xor(sum, 2);
      sum += __shfl_xor(sum, 4);
      sum += __shfl_xor(sum, 8);
      if (c16 == 0) Rinv[row] = 1.f / sum;
    }
    __syncthreads();

    // PV: wave = (strip = w>>2, nt = w&3); V from LDS
    {
      const int strip = w >> 2, nt = w & 3;
      const int sB = s0 + strip * 16;
      floatx4 oacc = {};
      for (int kc = 0; kc <= st; ++kc) {
        const float* prow = &Sc[strip * 16 + l15][kc * 32 + quad * 8];
        bf16x8 pa;
        pa[0] = (short)f2bf(prow[0]); pa[1] = (short)f2bf(prow[1]);
        pa[2] = (short)f2bf(prow[2]); pa[3] = (short)f2bf(prow[3]);
        pa[4] = (short)f2bf(prow[4]); pa[5] = (short)f2bf(prow[5]);
        pa[6] = (short)f2bf(prow[6]); pa[7] = (short)f2bf(prow[7]);
        const u16* vp = &Vt[nt * 16 + l15][kc * 32 + quad * 8];
        bf16x8 vbf = *(const bf16x8*)vp;
        oacc = MFMA16(pa, vbf, oacc);
      }
#pragma unroll
      for (int r = 0; r < 4; ++r) {
        float ivr = Rinv[strip * 16 + quad * 4 + r];
        int srow = sB + quad * 4 + r;
        vw[(size_t)(b * 256 + srow) * 1024 + h * 64 + nt * 16 + l15] =
            f2bf(oacc[r] * ivr);
      }
    }
    __syncthreads();
  }
}

extern "C" void kernel_launch(void* const* d_in, const int* in_sizes, int n_in,
                              void* d_out, int out_size, void* d_ws, size_t ws_size,
                              hipStream_t stream) {
  const float* x  = (const float*)d_in[0];
  const float* Wq = (const float*)d_in[1];
  const float* bq = (const float*)d_in[2];
  const float* Wk = (const float*)d_in[3];
  const float* bk = (const float*)d_in[4];
  const float* Wv = (const float*)d_in[5];
  const float* bv = (const float*)d_in[6];
  const float* Wr = (const float*)d_in[7];
  const float* br = (const float*)d_in[8];
  const float* ub = (const float*)d_in[9];
  const float* vb = (const float*)d_in[10];
  const float* Wo = (const float*)d_in[11];
  const float* bo = (const float*)d_in[12];
  float* out = (float*)d_out;

  char* base = (char*)d_ws;
  size_t off = 0;
  auto alloc = [&](size_t bytes) {
    void* p = base + off;
    off += (bytes + 255) & ~(size_t)255;
    return p;
  };

  const size_t MAT = (size_t)4194304;  // 4096*1024
  u16*   xA    = (u16*)alloc((size_t)4352 * 1024 * 2);       // [x ; table]
  u16*   W3b   = (u16*)alloc((size_t)3200 * 1024 * 2);       // [Wq;Wv;Wk;UV;pad]
  u16*   Wob   = (u16*)alloc((size_t)1024 * 1024 * 2);
  float* b3    = (float*)alloc((size_t)3200 * 4);            // [bq;bv;bk;ub.br;vb.br;0]
  u16*   Ph    = (u16*)alloc((3 * MAT + 262144) * 2);        // Qh,Vh,Kh,RPKh
  float* utb   = (float*)alloc((size_t)65536 * 4);
  float* dtb   = (float*)alloc((size_t)4096 * 4);
  u16*   vwb   = (u16*)alloc((size_t)4096 * 1024 * 2);

  u16* Qh   = Ph;
  u16* Vh   = Ph + MAT;
  u16* Kh   = Ph + 2 * MAT;
  u16* RPKh = Ph + 3 * MAT;

  // pack + table: (4194304 + 4194304 + 3072 + 262144)/1024 = 8451 blocks
  pack_k<<<dim3(8451), dim3(256), 0, stream>>>(x, Wq, Wk, Wv, Wo, bq, bk, bv,
                                               xA, W3b, Wob, b3);
  // rank-16 fold of Wr with u/v biases -> W3b rows 3072.., b3 tail
  uv_fold_k<<<dim3(128), dim3(256), 0, stream>>>(Wr, br, ub, vb, W3b, b3);

  // fused Q|V|K + relpos-K + ut/dt projections: 4352 x 3200 x 1024
  gemm_k<2, 128><<<dim3(25, 34), dim3(256), 0, stream>>>(xA, W3b, b3, Ph,
                                                         4352, 3200, 1024, utb, dtb);

  // fused attention: one block per (b,h)
  attn_k<<<dim3(256), dim3(512), 0, stream>>>(Qh, Kh, Vh, RPKh, utb, dtb, vwb);

  // output projection: 4096 x 1024 x 1024, fp32 out, 64x128 tiles (512 blocks)
  gemm_k<0, 64><<<dim3(8, 64), dim3(128), 0, stream>>>(vwb, Wob, bo, out,
                                                       4096, 1024, 1024, nullptr, nullptr);
}

// Round 9
// 230.994 us; speedup vs baseline: 1.9912x; 1.0163x over previous
//
#include <hip/hip_runtime.h>
#include <math.h>

constexpr int kB  = 16;
constexpr int kS  = 256;
constexpr int kD  = 1024;
constexpr int kH  = 16;
constexpr float kScale = 0.125f;  // 1/sqrt(64)

using bf16x8  = __attribute__((ext_vector_type(8))) short;
using floatx4 = __attribute__((ext_vector_type(4))) float;
typedef unsigned short u16;

__device__ __forceinline__ u16 f2bf(float x) {
  union { float f; unsigned u; } v; v.f = x;
  unsigned r = v.u + 0x7fffu + ((v.u >> 16) & 1u);
  return (u16)(r >> 16);
}
__device__ __forceinline__ float bf2f(u16 h) {
  union { unsigned u; float f; } v; v.u = ((unsigned)h) << 16;
  return v.f;
}

#define MFMA16(a, b, c) __builtin_amdgcn_mfma_f32_16x16x32_bf16((a), (b), (c), 0, 0, 0)
#define GLL16(gp, lp)                                                        \
  __builtin_amdgcn_global_load_lds(                                          \
      (const __attribute__((address_space(1))) unsigned int*)(gp),           \
      (__attribute__((address_space(3))) unsigned int*)(lp), 16, 0, 0)

// ---------------- pack + table: xA=[x;table], W3=[Wq;Wv;Wk], Wo, b3 ----------
__global__ __launch_bounds__(256) void pack_k(
    const float* __restrict__ x, const float* __restrict__ Wq,
    const float* __restrict__ Wk, const float* __restrict__ Wv,
    const float* __restrict__ Wo,
    const float* __restrict__ bq, const float* __restrict__ bk,
    const float* __restrict__ bv,
    u16* __restrict__ xA, u16* __restrict__ W3b, u16* __restrict__ Wob,
    float* __restrict__ b3) {
  size_t i = ((size_t)blockIdx.x * 256 + threadIdx.x) * 4;
  const size_t NX = (size_t)4194304, NW = (size_t)1048576;
  const size_t BEND = NX + 4 * NW + 3072;
  const float* src;
  u16* dst;
  size_t o;
  if (i < NX) {
    src = x; dst = xA; o = i;
  } else if (i < NX + 3 * NW) {
    size_t j = i - NX;
    int sel = (int)(j >> 20);
    o = j & (NW - 1);
    src = sel == 0 ? Wq : sel == 1 ? Wv : Wk;
    dst = W3b + (size_t)sel * NW;
  } else if (i < NX + 4 * NW) {
    o = i - NX - 3 * NW;
    src = Wo; dst = Wob;
  } else if (i < BEND) {
    size_t j = i - NX - 4 * NW;
    int sel = (int)(j >> 10);
    o = j & 1023;
    src = sel == 0 ? bq : sel == 1 ? bv : bk;
    *reinterpret_cast<float4*>(b3 + j) = *reinterpret_cast<const float4*>(src + o);
    return;
  } else if (i < BEND + 262144) {
    // sinusoid table rows p in [0,256), pos = p-255 -> xA rows 4096..4351
    size_t j = i - BEND;
    int p = (int)(j >> 10);
    int ibase = (int)(j & 1023);
    ushort4 r;
    u16* rr = (u16*)&r;
#pragma unroll
    for (int c = 0; c < 4; ++c) {
      int idx = ibase + c;
      float ex = (float)(2 * (idx / 2)) * (1.0f / 1024.0f);
      float scale = exp2f(ex * -13.287712379549449f);  // 10000^-ex
      float angle = (float)(p - 255) * scale;
      rr[c] = f2bf((idx & 1) ? cosf(angle) : sinf(angle));
    }
    *reinterpret_cast<ushort4*>(xA + NX + j) = r;
    return;
  } else {
    return;
  }
  float4 v = *reinterpret_cast<const float4*>(src + o);
  ushort4 r;
  r.x = f2bf(v.x); r.y = f2bf(v.y); r.z = f2bf(v.z); r.w = f2bf(v.w);
  *reinterpret_cast<ushort4*>(dst + o) = r;
}

// ---------------- rank-16 fold of Wr with u/v: W3b rows 3072..3103, b3 tail ------
// W3b[3072+j][c] = sum_d bvec_j[d] * Wr[(j&15)*64+d][c],  bvec = u (j<16) / v.
// b3[3072+j] = bvec_j . br_seg ; b3[3104..3199] = 0.
__global__ __launch_bounds__(256) void uv_fold_k(
    const float* __restrict__ Wr, const float* __restrict__ br,
    const float* __restrict__ ub, const float* __restrict__ vb,
    u16* __restrict__ W3b, float* __restrict__ b3) {
  int gid = blockIdx.x * 256 + threadIdx.x;  // 32768
  int j = gid >> 10, c = gid & 1023;
  int h = j & 15;
  const float* bvec = (j < 16 ? ub : vb) + h * 64;
  const float* wcol = Wr + (size_t)(h * 64) * 1024 + c;
  float a = 0.f;
#pragma unroll
  for (int d = 0; d < 64; ++d) a += bvec[d] * wcol[(size_t)d * 1024];
  W3b[(size_t)(3072 + j) * 1024 + c] = f2bf(a);
  if (gid < 128) {
    float s = 0.f;
    if (gid < 32) {
      const float* bv2 = (gid < 16 ? ub : vb) + (gid & 15) * 64;
      const float* brp = br + (gid & 15) * 64;
      for (int d = 0; d < 64; ++d) s += bv2[d] * brp[d];
    }
    b3[3072 + gid] = s;
  }
}

// ---------------- bf16 MFMA GEMM: C = A @ W^T + bias ----------------
// 128x128 tile, 256 threads (2x2 waves), BK=64, GLL16 staging, XOR-swizzled LDS.
// 1D grid with XCD-aware swizzle (xcd = blockIdx.x & 7 heuristic): each XCD owns
// a contiguous slab of m-tiles and iterates bn-major within it so B panels are
// read once per XCD and A slab panels stay hot in that XCD's 4 MB L2.
// OUT_MODE 0: fp32 flat row-major.
// OUT_MODE 2: head-major multi-tensor epilogue; rows >= 4096 are table rows;
//   cols 3072..3087 -> utb fp32, 3088..3103 -> dtb fp32, >=3104 discarded.
template <int OUT_MODE>
__global__ __launch_bounds__(256) void gemm_k(
    const u16* __restrict__ A, const u16* __restrict__ W,
    const float* __restrict__ bias, void* __restrict__ Cv,
    int M, int N, int K, float* __restrict__ utb, float* __restrict__ dtb,
    int mTiles, int nTiles) {
  const int xcd = blockIdx.x & 7;
  const int li  = blockIdx.x >> 3;
  const int r0   = (xcd * mTiles) >> 3;
  const int rcnt = (((xcd + 1) * mTiles) >> 3) - r0;
  if (li >= rcnt * nTiles) return;   // uniform early-out (padded grid)
  const int bm = (r0 + li % rcnt) * 128;
  const int bn = (li / rcnt) * 128;

  __shared__ u16 Alds[128 * 64];
  __shared__ u16 Blds[128 * 64];
  const int t = threadIdx.x, w = t >> 6, l = t & 63;
  const int l15 = l & 15, quad = l >> 4;
  const int wm = w >> 1, wn = w & 1;
  const int lrow8 = l >> 3;
  const int kslot = l & 7;

  floatx4 acc[4][4] = {};

  for (int k0 = 0; k0 < K; k0 += 64) {
#pragma unroll
    for (int sg = 0; sg < 4; ++sg) {
      int mrow = sg * 32 + w * 8 + lrow8;
      int gk = (kslot ^ (mrow & 7)) << 3;
      GLL16(A + (size_t)(bm + mrow) * K + k0 + gk, Alds + (sg * 32 + w * 8) * 64);
      GLL16(W + (size_t)(bn + mrow) * K + k0 + gk, Blds + (sg * 32 + w * 8) * 64);
    }
    __syncthreads();
#pragma unroll
    for (int c = 0; c < 2; ++c) {
      bf16x8 af[4], bf[4];
#pragma unroll
      for (int mi = 0; mi < 4; ++mi) {
        int am = wm * 64 + mi * 16 + l15;
        af[mi] = *(const bf16x8*)(Alds + am * 64 + (((c * 4 + quad) ^ (am & 7)) << 3));
      }
#pragma unroll
      for (int ni = 0; ni < 4; ++ni) {
        int an = wn * 64 + ni * 16 + l15;
        bf[ni] = *(const bf16x8*)(Blds + an * 64 + (((c * 4 + quad) ^ (an & 7)) << 3));
      }
#pragma unroll
      for (int mi = 0; mi < 4; ++mi)
#pragma unroll
        for (int ni = 0; ni < 4; ++ni)
          acc[mi][ni] = MFMA16(af[mi], bf[ni], acc[mi][ni]);
    }
    __syncthreads();
  }

#pragma unroll
  for (int ni = 0; ni < 4; ++ni) {
    int col = bn + wn * 64 + ni * 16 + l15;
    float bv = bias[col];
#pragma unroll
    for (int mi = 0; mi < 4; ++mi) {
      int mrow = bm + wm * 64 + mi * 16 + quad * 4;
#pragma unroll
      for (int r = 0; r < 4; ++r) {
        float v = acc[mi][ni][r] + bv;
        int row = mrow + r;
        if (OUT_MODE == 0) {
          ((float*)Cv)[(size_t)row * N + col] = v;
        } else {
          if (col < 3072) {
            int matsel = col >> 10;        // 0=Q,1=V,2=K
            int hh = (col >> 6) & 15, dd = col & 63;
            if (row < 4096) {
              int bb = row >> 8, ss = row & 255;
              ((u16*)Cv)[(size_t)matsel * 4194304 +
                         ((size_t)(((bb << 4) + hh) << 8) + ss) * 64 + dd] = f2bf(v);
            } else if (matsel == 2) {      // table @ Wk^T -> RPKh
              int pp = row - 4096;
              ((u16*)Cv)[(size_t)3 * 4194304 +
                         ((size_t)((hh << 8) + pp)) * 64 + dd] = f2bf(v);
            }
          } else if (col < 3088) {
            if (row < 4096)
              utb[((row >> 8) * 16 + (col - 3072)) * 256 + (row & 255)] = v;
          } else if (col < 3104) {
            if (row >= 4096)
              dtb[(col - 3088) * 256 + (row - 4096)] = v;
          }
        }
      }
    }
  }
}

// ---------------- fused attention: one block per (b,h), K/V in LDS ----------------
// 512 threads (8 waves). K staged via global_load_lds (XOR-swizzled); V
// transposed into LDS at staging; ut/dt preloaded (computed by GEMM fold).
// QK writes Sc[s][z], QR writes Sc2[s][p]; softmax combines via p = z-s+255.
// All frag-array indices compile-time (round-3 lesson).
__global__ __launch_bounds__(512, 2) void attn_k(
    const u16* __restrict__ Qh, const u16* __restrict__ Kh,
    const u16* __restrict__ Vh, const u16* __restrict__ RPKh,
    const float* __restrict__ ut, const float* __restrict__ dt,
    u16* __restrict__ vw) {
  __shared__ u16 Klds[256 * 64];     // 32 KB, XOR-swizzled rows
  __shared__ u16 Vt[64][280];        // 35 KB, V transposed
  __shared__ float Sc[32][257];      // scores by z
  __shared__ float Sc2[32][257];     // rel scores by p
  __shared__ float Ut[256], Dt[256], Rinv[32];

  const int bh = blockIdx.x;         // b*16 + h
  const int h = bh & 15;
  const int b = bh >> 4;
  const size_t bh256 = (size_t)bh << 8;

  const int t = threadIdx.x, w = t >> 6, l = t & 63;
  const int l15 = l & 15, quad = l >> 4;

  // ---- staging: K (GLL16), V^T (LDS transpose), Ut, Dt ----
  {
    const int lrow8 = l >> 3, kslot = l & 7;
#pragma unroll
    for (int i = 0; i < 4; ++i) {
      int row = w * 32 + i * 8 + lrow8;
      int gk = (kslot ^ (row & 7)) << 3;
      GLL16(Kh + (bh256 + row) * 64 + gk, Klds + (w * 32 + i * 8) * 64);
    }
  }
  {
    int z = t & 255, dh = t >> 8;    // dh: 0..1 (wave-uniform)
    const u16* gp = Vh + (bh256 + z) * 64 + dh * 32;
    ushort4 vv[8];
#pragma unroll
    for (int i = 0; i < 8; ++i) vv[i] = *(const ushort4*)(gp + i * 4);
#pragma unroll
    for (int i = 0; i < 8; ++i) {
      Vt[dh * 32 + i * 4 + 0][z] = vv[i].x;
      Vt[dh * 32 + i * 4 + 1][z] = vv[i].y;
      Vt[dh * 32 + i * 4 + 2][z] = vv[i].z;
      Vt[dh * 32 + i * 4 + 3][z] = vv[i].w;
    }
  }
  if (t < 256) Ut[t] = ut[bh256 + t];
  else         Dt[t - 256] = dt[((size_t)h << 8) + (t - 256)];
  __syncthreads();

  // ---- loop over 8 s-tiles of 32 rows ----
  for (int st = 0; st < 8; ++st) {
    const int s0 = st * 32;

    bf16x8 qa[2][2];
#pragma unroll
    for (int rt = 0; rt < 2; ++rt) {
      const u16* qp = Qh + (bh256 + s0 + rt * 16 + l15) * 64 + quad * 8;
      qa[rt][0] = *(const bf16x8*)qp;
      qa[rt][1] = *(const bf16x8*)(qp + 32);
    }

    // merged QK (-> Sc) + QR (-> Sc2); tasks round-robin over 8 waves
    {
      int cnt = 0;
#pragma unroll
      for (int rt = 0; rt < 2; ++rt) {
        const int rB = s0 + rt * 16;
        const int nzt = 2 * st + rt + 1;
        for (int zt = 0; zt < nzt; ++zt, ++cnt) {
          if ((cnt & 7) != w) continue;  // wave-uniform
          const int zr = (zt << 4) + l15;
          const u16* krow = Klds + zr * 64;
          bf16x8 kb0 = *(const bf16x8*)(krow + ((quad ^ (zr & 7)) << 3));
          bf16x8 kb1 = *(const bf16x8*)(krow + (((quad + 4) ^ (zr & 7)) << 3));
          floatx4 acc = {};
          acc = MFMA16(qa[rt][0], kb0, acc);
          acc = MFMA16(qa[rt][1], kb1, acc);
          float u = Ut[zr];
#pragma unroll
          for (int r = 0; r < 4; ++r)
            Sc[rt * 16 + quad * 4 + r][zr] = acc[r] + u;
        }
        for (int j = 0; j < nzt; ++j, ++cnt) {
          if ((cnt & 7) != w) continue;
          const int pr = 240 - rB + (j << 4) + l15;
          const u16* rp = RPKh + ((size_t)(h << 8) + pr) * 64 + quad * 8;
          bf16x8 rb0 = *(const bf16x8*)rp;
          bf16x8 rb1 = *(const bf16x8*)(rp + 32);
          floatx4 acc = {};
          acc = MFMA16(qa[rt][0], rb0, acc);
          acc = MFMA16(qa[rt][1], rb1, acc);
          float dv = Dt[pr];
#pragma unroll
          for (int r = 0; r < 4; ++r)
            Sc2[rt * 16 + quad * 4 + r][pr] = acc[r] + dv;
        }
      }
    }
    __syncthreads();

    // softmax: 4 rows/wave, 16 lanes/row; P -> Sc
    {
      const int row = w * 4 + (l >> 4);
      const int c16 = l & 15;
      const int s = s0 + row;
      const int zfill = 32 * (st + 1);
      float m = -1e30f;
      for (int z = c16; z <= s; z += 16)
        m = fmaxf(m, Sc[row][z] + Sc2[row][z - s + 255]);
      m = fmaxf(m, __shfl_xor(m, 1));
      m = fmaxf(m, __shfl_xor(m, 2));
      m = fmaxf(m, __shfl_xor(m, 4));
      m = fmaxf(m, __shfl_xor(m, 8));
      m *= kScale;
      float sum = 0.f;
      for (int z = c16; z < zfill; z += 16) {
        float e = 0.f;
        if (z <= s) {
          e = __expf((Sc[row][z] + Sc2[row][z - s + 255]) * kScale - m);
          sum += e;
        }
        Sc[row][z] = e;
      }
      sum += __shfl_xor(sum, 1);
      sum += __shfl_xor(sum, 2);
      sum += __shfl_xor(sum, 4);
      sum += __shfl_xor(sum, 8);
      if (c16 == 0) Rinv[row] = 1.f / sum;
    }
    __syncthreads();

    // PV: wave = (strip = w>>2, nt = w&3); V from LDS
    {
      const int strip = w >> 2, nt = w & 3;
      const int sB = s0 + strip * 16;
      floatx4 oacc = {};
      for (int kc = 0; kc <= st; ++kc) {
        const float* prow = &Sc[strip * 16 + l15][kc * 32 + quad * 8];
        bf16x8 pa;
        pa[0] = (short)f2bf(prow[0]); pa[1] = (short)f2bf(prow[1]);
        pa[2] = (short)f2bf(prow[2]); pa[3] = (short)f2bf(prow[3]);
        pa[4] = (short)f2bf(prow[4]); pa[5] = (short)f2bf(prow[5]);
        pa[6] = (short)f2bf(prow[6]); pa[7] = (short)f2bf(prow[7]);
        const u16* vp = &Vt[nt * 16 + l15][kc * 32 + quad * 8];
        bf16x8 vbf = *(const bf16x8*)vp;
        oacc = MFMA16(pa, vbf, oacc);
      }
#pragma unroll
      for (int r = 0; r < 4; ++r) {
        float ivr = Rinv[strip * 16 + quad * 4 + r];
        int srow = sB + quad * 4 + r;
        vw[(size_t)(b * 256 + srow) * 1024 + h * 64 + nt * 16 + l15] =
            f2bf(oacc[r] * ivr);
      }
    }
    __syncthreads();
  }
}

extern "C" void kernel_launch(void* const* d_in, const int* in_sizes, int n_in,
                              void* d_out, int out_size, void* d_ws, size_t ws_size,
                              hipStream_t stream) {
  const float* x  = (const float*)d_in[0];
  const float* Wq = (const float*)d_in[1];
  const float* bq = (const float*)d_in[2];
  const float* Wk = (const float*)d_in[3];
  const float* bk = (const float*)d_in[4];
  const float* Wv = (const float*)d_in[5];
  const float* bv = (const float*)d_in[6];
  const float* Wr = (const float*)d_in[7];
  const float* br = (const float*)d_in[8];
  const float* ub = (const float*)d_in[9];
  const float* vb = (const float*)d_in[10];
  const float* Wo = (const float*)d_in[11];
  const float* bo = (const float*)d_in[12];
  float* out = (float*)d_out;

  char* base = (char*)d_ws;
  size_t off = 0;
  auto alloc = [&](size_t bytes) {
    void* p = base + off;
    off += (bytes + 255) & ~(size_t)255;
    return p;
  };

  const size_t MAT = (size_t)4194304;  // 4096*1024
  u16*   xA    = (u16*)alloc((size_t)4352 * 1024 * 2);       // [x ; table]
  u16*   W3b   = (u16*)alloc((size_t)3200 * 1024 * 2);       // [Wq;Wv;Wk;UV;pad]
  u16*   Wob   = (u16*)alloc((size_t)1024 * 1024 * 2);
  float* b3    = (float*)alloc((size_t)3200 * 4);            // [bq;bv;bk;ub.br;vb.br;0]
  u16*   Ph    = (u16*)alloc((3 * MAT + 262144) * 2);        // Qh,Vh,Kh,RPKh
  float* utb   = (float*)alloc((size_t)65536 * 4);
  float* dtb   = (float*)alloc((size_t)4096 * 4);
  u16*   vwb   = (u16*)alloc((size_t)4096 * 1024 * 2);

  u16* Qh   = Ph;
  u16* Vh   = Ph + MAT;
  u16* Kh   = Ph + 2 * MAT;
  u16* RPKh = Ph + 3 * MAT;

  // pack + table: (4194304 + 4194304 + 3072 + 262144)/1024 = 8451 blocks
  pack_k<<<dim3(8451), dim3(256), 0, stream>>>(x, Wq, Wk, Wv, Wo, bq, bk, bv,
                                               xA, W3b, Wob, b3);
  // rank-16 fold of Wr with u/v biases -> W3b rows 3072.., b3 tail
  uv_fold_k<<<dim3(128), dim3(256), 0, stream>>>(Wr, br, ub, vb, W3b, b3);

  // fused Q|V|K + relpos-K + ut/dt projections: 4352 x 3200 x 1024
  // mTiles=34, nTiles=25; padded 1D grid = 8 * ceil(34/8)*25 = 1000
  gemm_k<2><<<dim3(1000), dim3(256), 0, stream>>>(xA, W3b, b3, Ph,
                                                  4352, 3200, 1024, utb, dtb, 34, 25);

  // fused attention: one block per (b,h)
  attn_k<<<dim3(256), dim3(512), 0, stream>>>(Qh, Kh, Vh, RPKh, utb, dtb, vwb);

  // output projection: 4096 x 1024 x 1024, fp32 out; mTiles=32, nTiles=8 -> 256
  gemm_k<0><<<dim3(256), dim3(256), 0, stream>>>(vwb, Wob, bo, out,
                                                 4096, 1024, 1024, nullptr, nullptr,
                                                 32, 8);
}